// Round 4
// baseline (553.039 us; speedup 1.0000x reference)
//
#include <hip/hip_runtime.h>
#include <hip/hip_bf16.h>
#include <stdint.h>

#define N 2048
#define D 128
#define H 40

typedef __attribute__((ext_vector_type(8))) short short8;
typedef __attribute__((ext_vector_type(4))) float float4v;
typedef __attribute__((ext_vector_type(16))) float float16v;

static __device__ __forceinline__ unsigned short f32_to_bf16(float f) {
  unsigned int u = __builtin_bit_cast(unsigned int, f);
  unsigned int rounding = 0x7FFFu + ((u >> 16) & 1u);
  return (unsigned short)((u + rounding) >> 16);
}

static __device__ __forceinline__ unsigned int pk2(float lo, float hi) {
  return (unsigned int)f32_to_bf16(lo) | ((unsigned int)f32_to_bf16(hi) << 16);
}

static __device__ __forceinline__ unsigned long long pack4(float x0, float x1,
                                                           float x2, float x3) {
  return (unsigned long long)pk2(x0, x1) | ((unsigned long long)pk2(x2, x3) << 32);
}

// Async global->LDS DMA, 16B/lane. LDS dest = wave-uniform base + lane*16.
static __device__ __forceinline__ void load_lds16(const void* g, void* l) {
  __builtin_amdgcn_global_load_lds(
      (const __attribute__((address_space(1))) unsigned int*)g,
      (__attribute__((address_space(3))) unsigned int*)l, 16, 0, 0);
}

#define MFMA32(a, b, c) __builtin_amdgcn_mfma_f32_32x32x16_bf16((a), (b), (c), 0, 0, 0)

// Convert 32x32 C-layout regs (m=(r&3)+8*(r>>2)+4*hh, col=l) into two
// B-fragments (k=hh*8+j): f0 covers m=0..15, f1 covers m=16..31.
// (Verified end-to-end in R3.)
static __device__ __forceinline__ void regs_to_bfrags(const float16v c, int hh,
                                                      short8& f0, short8& f1) {
  unsigned int a0 = pk2(c[0], c[1]),   a1 = pk2(c[2], c[3]);
  unsigned int a2 = pk2(c[4], c[5]),   a3 = pk2(c[6], c[7]);
  unsigned int a4 = pk2(c[8], c[9]),   a5 = pk2(c[10], c[11]);
  unsigned int a6 = pk2(c[12], c[13]), a7 = pk2(c[14], c[15]);
  unsigned int x0 = __shfl_xor(hh ? a0 : a2, 32);
  unsigned int x1 = __shfl_xor(hh ? a1 : a3, 32);
  unsigned int x2 = __shfl_xor(hh ? a4 : a6, 32);
  unsigned int x3 = __shfl_xor(hh ? a5 : a7, 32);
  uint4 u0 = {hh ? x0 : a0, hh ? x1 : a1, hh ? a2 : x0, hh ? a3 : x1};
  uint4 u1 = {hh ? x2 : a4, hh ? x3 : a5, hh ? a6 : x2, hh ? a7 : x3};
  f0 = __builtin_bit_cast(short8, u0);
  f1 = __builtin_bit_cast(short8, u1);
}

// Same, but exp() first and accumulate the row-sum (softmax denominator).
static __device__ __forceinline__ void regs_to_pfrags(const float16v s, int hh,
                                                      float& lsum, short8& f0,
                                                      short8& f1) {
  float e[16];
  float acc = 0.0f;
#pragma unroll
  for (int i = 0; i < 16; i++) { e[i] = __expf(s[i]); acc += e[i]; }
  lsum += acc;
  unsigned int a0 = pk2(e[0], e[1]),   a1 = pk2(e[2], e[3]);
  unsigned int a2 = pk2(e[4], e[5]),   a3 = pk2(e[6], e[7]);
  unsigned int a4 = pk2(e[8], e[9]),   a5 = pk2(e[10], e[11]);
  unsigned int a6 = pk2(e[12], e[13]), a7 = pk2(e[14], e[15]);
  unsigned int x0 = __shfl_xor(hh ? a0 : a2, 32);
  unsigned int x1 = __shfl_xor(hh ? a1 : a3, 32);
  unsigned int x2 = __shfl_xor(hh ? a4 : a6, 32);
  unsigned int x3 = __shfl_xor(hh ? a5 : a7, 32);
  uint4 u0 = {hh ? x0 : a0, hh ? x1 : a1, hh ? a2 : x0, hh ? a3 : x1};
  uint4 u1 = {hh ? x2 : a4, hh ? x3 : a5, hh ? a6 : x2, hh ? a7 : x3};
  f0 = __builtin_bit_cast(short8, u0);
  f1 = __builtin_bit_cast(short8, u1);
}

// ---- X fp32 -> Xb [n][d] bf16 and XbT [d][n] bf16 (16 blocks x 128 rows) ----
__global__ __launch_bounds__(256)
void xconv_kernel(const float* __restrict__ X, unsigned short* __restrict__ Xb,
                  unsigned short* __restrict__ XbT) {
  const int n0 = blockIdx.x * 128;
  const int tid = threadIdx.x;
  __shared__ __align__(16) unsigned short Lt[128 * 136];  // [n][d], pad 8
  for (int i = tid; i < 128 * 32; i += 256) {
    int row = i >> 5, c4 = (i & 31) * 4;
    float4v x = *(const float4v*)(X + (size_t)(n0 + row) * D + c4);
    unsigned long long p = pack4(x.x, x.y, x.z, x.w);
    *(unsigned long long*)(Lt + row * 136 + c4) = p;
    *(unsigned long long*)(Xb + (size_t)(n0 + row) * D + c4) = p;
  }
  __syncthreads();
  for (int i = tid; i < 128 * 16; i += 256) {
    int d = i >> 4, g = i & 15;
    short8 v;
#pragma unroll
    for (int j = 0; j < 8; j++) v[j] = (short)Lt[(g * 8 + j) * 136 + d];
    *(short8*)(XbT + (size_t)d * N + n0 + g * 8) = v;
  }
}

// ---- W/V fp32 -> bf16, transposed: Wt[h][e][d] (W pre-scaled by 1/sqrt(D)) ----
__global__ __launch_bounds__(256)
void wvconv_kernel(const float* __restrict__ W, const float* __restrict__ V,
                   unsigned short* __restrict__ Wt, unsigned short* __restrict__ Vt) {
  const int b = blockIdx.x;
  const int mat = (b >= H) ? 1 : 0;
  const int h = mat ? b - H : b;
  const float* src = (mat ? V : W) + (size_t)h * D * D;
  unsigned short* dst = (mat ? Vt : Wt) + (size_t)h * D * D;
  const float scale = mat ? 1.0f : 0.08838834764831845f;
  const int tid = threadIdx.x;
  __shared__ __align__(16) unsigned short Lt[128 * 136];  // [e][d], pad 8
  for (int i = tid; i < 128 * 32; i += 256) {
    int d = i >> 5, e4 = (i & 31) * 4;
    float4v w = *(const float4v*)(src + d * D + e4);
    Lt[(e4 + 0) * 136 + d] = f32_to_bf16(w.x * scale);
    Lt[(e4 + 1) * 136 + d] = f32_to_bf16(w.y * scale);
    Lt[(e4 + 2) * 136 + d] = f32_to_bf16(w.z * scale);
    Lt[(e4 + 3) * 136 + d] = f32_to_bf16(w.w * scale);
  }
  __syncthreads();
  for (int i = tid; i < 128 * 16; i += 256) {
    int e = i >> 4, u = i & 15;
    *(uint4*)((char*)dst + (size_t)e * 256 + u * 16) =
        *(const uint4*)((const char*)Lt + (size_t)e * 272 + u * 16);
  }
}

// ---- attention: Q-prologue, flash loop accumulating T = P@X, epilogue T@V ----
__global__ __launch_bounds__(256, 2)
void attn_kernel(const unsigned short* __restrict__ Xb,
                 const unsigned short* __restrict__ XbT,
                 const unsigned short* __restrict__ Wt,
                 const unsigned short* __restrict__ Vt,
                 float* __restrict__ out) {
  __shared__ __align__(16) char smem[65536];  // region0: Xq/K/Lred/Ls  region1: Wt/XsT/Vt/Ls
  const int bx = blockIdx.x;
  const int h = bx >> 4;
  const int q0 = (bx & 15) << 7;
  const int tid = threadIdx.x;
  const int wave = tid >> 6, lane = tid & 63;
  const int l = lane & 31, hh = lane >> 5;
  const int sw = l & 15;  // full 16-unit XOR swizzle (kills 4-way b128 aliasing)
  const int kw = wave & 1, qw = wave >> 1;
  const int lh = lane >> 4, lu = lane & 15;

  const char* XbB = (const char*)Xb;
  const char* XbTB = (const char*)XbT;
  const char* WtB = (const char*)(Wt + (size_t)h * D * D);
  const char* VtB = (const char*)(Vt + (size_t)h * D * D);

  // ---- prologue: stage X(q-tile) + Wt[h], compute Q fragments in registers
#pragma unroll
  for (int i = 0; i < 8; i++) {
    int r = wave * 32 + i * 4 + lh;
    int us = lu ^ (r & 15);
    load_lds16(XbB + (size_t)(q0 + r) * 256 + us * 16, smem + (wave * 8 + i) * 1024);
    load_lds16(WtB + (size_t)r * 256 + us * 16, smem + 32768 + (wave * 8 + i) * 1024);
  }
  __syncthreads();

  short8 qf[8][2];  // [dks][qc] : B-frags Q^T[d][q]
  {
    short8 xf[2][8];
#pragma unroll
    for (int qc = 0; qc < 2; qc++)
#pragma unroll
      for (int dk = 0; dk < 8; dk++)
        xf[qc][dk] = *(const short8*)(smem +
                     ((qw * 64 + qc * 32 + l) * 16 + ((2 * dk + hh) ^ sw)) * 16);
#pragma unroll
    for (int et = 0; et < 4; et++) {
      float16v qa0 = (float16v)0.0f, qa1 = (float16v)0.0f;
#pragma unroll
      for (int dk = 0; dk < 8; dk++) {
        short8 wa = *(const short8*)(smem + 32768 +
                     ((et * 32 + l) * 16 + ((2 * dk + hh) ^ sw)) * 16);
        qa0 = MFMA32(wa, xf[0][dk], qa0);
        qa1 = MFMA32(wa, xf[1][dk], qa1);
      }
      regs_to_bfrags(qa0, hh, qf[2 * et][0], qf[2 * et + 1][0]);
      regs_to_bfrags(qa1, hh, qf[2 * et][1], qf[2 * et + 1][1]);
    }
  }

  float16v Tacc[4][2];  // T^T[d][q] partial over this wave's (kw) keys
#pragma unroll
  for (int dt = 0; dt < 4; dt++) { Tacc[dt][0] = (float16v)0.0f; Tacc[dt][1] = (float16v)0.0f; }
  float lsum[2] = {0.0f, 0.0f};

  for (int kt = 0; kt < N / 128; kt++) {
    const int k0 = kt * 128;
    __syncthreads();
#pragma unroll
    for (int i = 0; i < 8; i++) {
      int r = wave * 32 + i * 4 + lh;
      int us = lu ^ (r & 15);
      load_lds16(XbB + (size_t)(k0 + r) * 256 + us * 16, smem + (wave * 8 + i) * 1024);
      load_lds16(XbTB + (size_t)r * 4096 + (size_t)k0 * 2 + us * 16,
                 smem + 32768 + (wave * 8 + i) * 1024);
    }
    __syncthreads();

#pragma unroll
    for (int ksub = 0; ksub < 2; ksub++) {
      short8 kf[8];
#pragma unroll
      for (int ks = 0; ks < 8; ks++)
        kf[ks] = *(const short8*)(smem +
                 ((kw * 64 + ksub * 32 + l) * 16 + ((2 * ks + hh) ^ sw)) * 16);
      short8 pf[2][2];  // [qc][kk]
#pragma unroll
      for (int qc = 0; qc < 2; qc++) {
        float16v s = (float16v)0.0f;
#pragma unroll
        for (int ks = 0; ks < 8; ks++) s = MFMA32(kf[ks], qf[ks][qc], s);
        regs_to_pfrags(s, hh, lsum[qc], pf[qc][0], pf[qc][1]);
      }
      // T^T += X_tile^T @ P^T  (A from XsT [d][k] tile, B = pf)
#pragma unroll
      for (int kk = 0; kk < 2; kk++)
#pragma unroll
        for (int dt = 0; dt < 4; dt++) {
          short8 xt = *(const short8*)(smem + 32768 +
                      ((dt * 32 + l) * 16 + ((kw * 8 + ksub * 4 + kk * 2 + hh) ^ sw)) * 16);
          Tacc[dt][0] = MFMA32(xt, pf[0][kk], Tacc[dt][0]);
          Tacc[dt][1] = MFMA32(xt, pf[1][kk], Tacc[dt][1]);
        }
    }
  }

  // ---- lsum reduction + Vt staging
  __syncthreads();
  float* Lred = (float*)smem;  // [2][128] in region0
#pragma unroll
  for (int qc = 0; qc < 2; qc++) {
    float t = lsum[qc] + __shfl_xor(lsum[qc], 32);
    if (hh == 0) Lred[kw * 128 + qw * 64 + qc * 32 + l] = t;
  }
#pragma unroll
  for (int i = 0; i < 8; i++) {
    int r = wave * 32 + i * 4 + lh;
    int us = lu ^ (r & 15);
    load_lds16(VtB + (size_t)r * 256 + us * 16, smem + 32768 + (wave * 8 + i) * 1024);
  }
  __syncthreads();
  float inv[2];
#pragma unroll
  for (int qc = 0; qc < 2; qc++) {
    int q = qw * 64 + qc * 32 + l;
    inv[qc] = 1.0f / (Lred[q] + Lred[128 + q]);
  }

  // ---- epilogue GEMM: out^T[e][q] = V^T[e][d] @ T^T[d][q]
  short8 tb[2][8];
#pragma unroll
  for (int qc = 0; qc < 2; qc++)
#pragma unroll
    for (int dt = 0; dt < 4; dt++)
      regs_to_bfrags(Tacc[dt][qc], hh, tb[qc][2 * dt], tb[qc][2 * dt + 1]);

  float16v oacc[4][2];
#pragma unroll
  for (int et = 0; et < 4; et++) { oacc[et][0] = (float16v)0.0f; oacc[et][1] = (float16v)0.0f; }
#pragma unroll
  for (int et = 0; et < 4; et++)
#pragma unroll
    for (int dk = 0; dk < 8; dk++) {
      short8 va = *(const short8*)(smem + 32768 +
                  ((et * 32 + l) * 16 + ((2 * dk + hh) ^ sw)) * 16);
      oacc[et][0] = MFMA32(va, tb[0][dk], oacc[et][0]);
      oacc[et][1] = MFMA32(va, tb[1][dk], oacc[et][1]);
    }
  __syncthreads();  // Vt + Lred consumed; smem becomes Ls [128 q][32 fp32x4 units]

#pragma unroll
  for (int pass = 0; pass < 2; pass++) {
    if (kw == pass) {
#pragma unroll
      for (int et = 0; et < 4; et++)
#pragma unroll
        for (int qc = 0; qc < 2; qc++) {
          int q = qw * 64 + qc * 32 + l;
#pragma unroll
          for (int g = 0; g < 4; g++) {
            int u = (et * 8 + 2 * g + hh) ^ (q & 15);
            float4v* p = (float4v*)(smem + (size_t)q * 512 + u * 16);
            float4v v;
            v.x = oacc[et][qc][4 * g + 0] * inv[qc];
            v.y = oacc[et][qc][4 * g + 1] * inv[qc];
            v.z = oacc[et][qc][4 * g + 2] * inv[qc];
            v.w = oacc[et][qc][4 * g + 3] * inv[qc];
            if (pass == 0) *p = v;
            else { float4v o = *p; o.x += v.x; o.y += v.y; o.z += v.z; o.w += v.w; *p = o; }
          }
        }
    }
    __syncthreads();
  }
#pragma unroll
  for (int i = 0; i < 16; i++) {
    int s = i * 256 + tid;
    int q = s >> 5, up = s & 31, u = up ^ (q & 15);
    float4v v = *(const float4v*)(smem + (size_t)q * 512 + up * 16);
    float* dst = out + (size_t)(q0 + q) * D + u * 4;
    atomicAdd(dst + 0, v.x);
    atomicAdd(dst + 1, v.y);
    atomicAdd(dst + 2, v.z);
    atomicAdd(dst + 3, v.w);
  }
}

extern "C" void kernel_launch(void* const* d_in, const int* in_sizes, int n_in,
                              void* d_out, int out_size, void* d_ws, size_t ws_size,
                              hipStream_t stream) {
  const float* X = (const float*)d_in[0];
  const float* W = (const float*)d_in[1];
  const float* V = (const float*)d_in[2];
  float* out = (float*)d_out;

  unsigned short* Xb = (unsigned short*)d_ws;     // N*D
  unsigned short* XbT = Xb + (size_t)N * D;       // D*N
  unsigned short* Wt = XbT + (size_t)N * D;       // H*D*D (scaled, transposed)
  unsigned short* Vt = Wt + (size_t)H * D * D;    // H*D*D (transposed)

  hipMemsetAsync(d_out, 0, (size_t)N * D * sizeof(float), stream);

  xconv_kernel<<<dim3(N / 128), 256, 0, stream>>>(X, Xb, XbT);
  wvconv_kernel<<<dim3(2 * H), 256, 0, stream>>>(W, V, Wt, Vt);
  attn_kernel<<<dim3((N / 128) * H), 256, 0, stream>>>(Xb, XbT, Wt, Vt, out);
}

// Round 6
// 375.287 us; speedup vs baseline: 1.4736x; 1.4736x over previous
//
#include <hip/hip_runtime.h>
#include <hip/hip_bf16.h>
#include <stdint.h>

#define N 2048
#define D 128
#define H 40

typedef __attribute__((ext_vector_type(8))) short short8;
typedef __attribute__((ext_vector_type(4))) float float4v;
typedef __attribute__((ext_vector_type(16))) float float16v;

static __device__ __forceinline__ unsigned short f32_to_bf16(float f) {
  unsigned int u = __builtin_bit_cast(unsigned int, f);
  unsigned int rounding = 0x7FFFu + ((u >> 16) & 1u);
  return (unsigned short)((u + rounding) >> 16);
}

// Pack two fp32 -> bf16x2 (RNE). Use HW v_cvt_pk_bf16_f32 when the builtin
// exists; otherwise manual bit-pack (verified R1-R4).
static __device__ __forceinline__ unsigned int pk2(float lo, float hi) {
#if __has_builtin(__builtin_amdgcn_cvt_pk_bf16_f32)
  typedef __attribute__((ext_vector_type(2))) __bf16 bf16x2;
  bf16x2 t = __builtin_amdgcn_cvt_pk_bf16_f32(lo, hi);
  return __builtin_bit_cast(unsigned int, t);
#else
  return (unsigned int)f32_to_bf16(lo) | ((unsigned int)f32_to_bf16(hi) << 16);
#endif
}

static __device__ __forceinline__ unsigned long long pack4(float x0, float x1,
                                                           float x2, float x3) {
  return (unsigned long long)pk2(x0, x1) | ((unsigned long long)pk2(x2, x3) << 32);
}

// Async global->LDS DMA, 16B/lane. LDS dest = wave-uniform base + lane*16.
static __device__ __forceinline__ void load_lds16(const void* g, void* l) {
  __builtin_amdgcn_global_load_lds(
      (const __attribute__((address_space(1))) unsigned int*)g,
      (__attribute__((address_space(3))) unsigned int*)l, 16, 0, 0);
}

#define MFMA32(a, b, c) __builtin_amdgcn_mfma_f32_32x32x16_bf16((a), (b), (c), 0, 0, 0)

// Convert 32x32 C-layout regs (m=(r&3)+8*(r>>2)+4*hh, col=l) into two
// B-fragments (k=hh*8+j): f0 covers m=0..15, f1 covers m=16..31. (Verified R3/R4.)
static __device__ __forceinline__ void regs_to_bfrags(const float16v c, int hh,
                                                      short8& f0, short8& f1) {
  unsigned int a0 = pk2(c[0], c[1]),   a1 = pk2(c[2], c[3]);
  unsigned int a2 = pk2(c[4], c[5]),   a3 = pk2(c[6], c[7]);
  unsigned int a4 = pk2(c[8], c[9]),   a5 = pk2(c[10], c[11]);
  unsigned int a6 = pk2(c[12], c[13]), a7 = pk2(c[14], c[15]);
  unsigned int x0 = __shfl_xor(hh ? a0 : a2, 32);
  unsigned int x1 = __shfl_xor(hh ? a1 : a3, 32);
  unsigned int x2 = __shfl_xor(hh ? a4 : a6, 32);
  unsigned int x3 = __shfl_xor(hh ? a5 : a7, 32);
  uint4 u0 = {hh ? x0 : a0, hh ? x1 : a1, hh ? a2 : x0, hh ? a3 : x1};
  uint4 u1 = {hh ? x2 : a4, hh ? x3 : a5, hh ? a6 : x2, hh ? a7 : x3};
  f0 = __builtin_bit_cast(short8, u0);
  f1 = __builtin_bit_cast(short8, u1);
}

// Same, but exp() first and accumulate the row-sum (softmax denominator).
static __device__ __forceinline__ void regs_to_pfrags(const float16v s, int hh,
                                                      float& lsum, short8& f0,
                                                      short8& f1) {
  float e[16];
  float acc = 0.0f;
#pragma unroll
  for (int i = 0; i < 16; i++) { e[i] = __expf(s[i]); acc += e[i]; }
  lsum += acc;
  unsigned int a0 = pk2(e[0], e[1]),   a1 = pk2(e[2], e[3]);
  unsigned int a2 = pk2(e[4], e[5]),   a3 = pk2(e[6], e[7]);
  unsigned int a4 = pk2(e[8], e[9]),   a5 = pk2(e[10], e[11]);
  unsigned int a6 = pk2(e[12], e[13]), a7 = pk2(e[14], e[15]);
  unsigned int x0 = __shfl_xor(hh ? a0 : a2, 32);
  unsigned int x1 = __shfl_xor(hh ? a1 : a3, 32);
  unsigned int x2 = __shfl_xor(hh ? a4 : a6, 32);
  unsigned int x3 = __shfl_xor(hh ? a5 : a7, 32);
  uint4 u0 = {hh ? x0 : a0, hh ? x1 : a1, hh ? a2 : x0, hh ? a3 : x1};
  uint4 u1 = {hh ? x2 : a4, hh ? x3 : a5, hh ? a6 : x2, hh ? a7 : x3};
  f0 = __builtin_bit_cast(short8, u0);
  f1 = __builtin_bit_cast(short8, u1);
}

// ---- X fp32 -> Xb [n][d] bf16 and XbT [d][n] bf16 (16 blocks x 128 rows) ----
__global__ __launch_bounds__(256)
void xconv_kernel(const float* __restrict__ X, unsigned short* __restrict__ Xb,
                  unsigned short* __restrict__ XbT) {
  const int n0 = blockIdx.x * 128;
  const int tid = threadIdx.x;
  __shared__ __align__(16) unsigned short Lt[128 * 136];  // [n][d], pad 8
  for (int i = tid; i < 128 * 32; i += 256) {
    int row = i >> 5, c4 = (i & 31) * 4;
    float4v x = *(const float4v*)(X + (size_t)(n0 + row) * D + c4);
    unsigned long long p = pack4(x.x, x.y, x.z, x.w);
    *(unsigned long long*)(Lt + row * 136 + c4) = p;
    *(unsigned long long*)(Xb + (size_t)(n0 + row) * D + c4) = p;
  }
  __syncthreads();
  for (int i = tid; i < 128 * 16; i += 256) {
    int d = i >> 4, g = i & 15;
    short8 v;
#pragma unroll
    for (int j = 0; j < 8; j++) v[j] = (short)Lt[(g * 8 + j) * 136 + d];
    *(short8*)(XbT + (size_t)d * N + n0 + g * 8) = v;
  }
}

// ---- W/V fp32 -> bf16, transposed: Wt[h][e][d] (W pre-scaled by 1/sqrt(D)) ----
__global__ __launch_bounds__(256)
void wvconv_kernel(const float* __restrict__ W, const float* __restrict__ V,
                   unsigned short* __restrict__ Wt, unsigned short* __restrict__ Vt) {
  const int b = blockIdx.x;
  const int mat = (b >= H) ? 1 : 0;
  const int h = mat ? b - H : b;
  const float* src = (mat ? V : W) + (size_t)h * D * D;
  unsigned short* dst = (mat ? Vt : Wt) + (size_t)h * D * D;
  const float scale = mat ? 1.0f : 0.08838834764831845f;
  const int tid = threadIdx.x;
  __shared__ __align__(16) unsigned short Lt[128 * 136];  // [e][d], pad 8
  for (int i = tid; i < 128 * 32; i += 256) {
    int d = i >> 5, e4 = (i & 31) * 4;
    float4v w = *(const float4v*)(src + d * D + e4);
    Lt[(e4 + 0) * 136 + d] = f32_to_bf16(w.x * scale);
    Lt[(e4 + 1) * 136 + d] = f32_to_bf16(w.y * scale);
    Lt[(e4 + 2) * 136 + d] = f32_to_bf16(w.z * scale);
    Lt[(e4 + 3) * 136 + d] = f32_to_bf16(w.w * scale);
  }
  __syncthreads();
  for (int i = tid; i < 128 * 16; i += 256) {
    int e = i >> 4, u = i & 15;
    *(uint4*)((char*)dst + (size_t)e * 256 + u * 16) =
        *(const uint4*)((const char*)Lt + (size_t)e * 272 + u * 16);
  }
}

// ---- attention: Q-prologue, flash loop accumulating T = P@X, epilogue T@V ----
// NOTE: no second __launch_bounds__ arg — (256,2) capped VGPRs at 128 and the
// ~260-reg live set spilled ~650 MB/launch to scratch (R3/R4 post-mortem).
__global__ __launch_bounds__(256)
void attn_kernel(const unsigned short* __restrict__ Xb,
                 const unsigned short* __restrict__ XbT,
                 const unsigned short* __restrict__ Wt,
                 const unsigned short* __restrict__ Vt,
                 float* __restrict__ out) {
  __shared__ __align__(16) char smem[65536];  // region0: Xq/K/Lred/Ls  region1: Wt/XsT/Vt/Ls
  const int bx = blockIdx.x;
  const int h = bx >> 4;
  const int q0 = (bx & 15) << 7;
  const int tid = threadIdx.x;
  const int wave = tid >> 6, lane = tid & 63;
  const int l = lane & 31, hh = lane >> 5;
  const int sw = l & 15;  // full 16-unit XOR swizzle (0 bank conflicts, R4)
  const int kw = wave & 1, qw = wave >> 1;
  const int lh = lane >> 4, lu = lane & 15;

  const char* XbB = (const char*)Xb;
  const char* XbTB = (const char*)XbT;
  const char* WtB = (const char*)(Wt + (size_t)h * D * D);
  const char* VtB = (const char*)(Vt + (size_t)h * D * D);

  // ---- prologue: stage X(q-tile) + Wt[h], compute Q fragments in registers
#pragma unroll
  for (int i = 0; i < 8; i++) {
    int r = wave * 32 + i * 4 + lh;
    int us = lu ^ (r & 15);
    load_lds16(XbB + (size_t)(q0 + r) * 256 + us * 16, smem + (wave * 8 + i) * 1024);
    load_lds16(WtB + (size_t)r * 256 + us * 16, smem + 32768 + (wave * 8 + i) * 1024);
  }
  __syncthreads();

  short8 qf[8][2];  // [dks][qc] : B-frags Q^T[d][q]
  {
#pragma unroll
    for (int et = 0; et < 4; et++) {
      float16v qa0 = (float16v)0.0f, qa1 = (float16v)0.0f;
#pragma unroll
      for (int dk = 0; dk < 8; dk++) {
        short8 wa = *(const short8*)(smem + 32768 +
                     ((et * 32 + l) * 16 + ((2 * dk + hh) ^ sw)) * 16);
        short8 xf0 = *(const short8*)(smem +
                     ((qw * 64 + l) * 16 + ((2 * dk + hh) ^ sw)) * 16);
        short8 xf1 = *(const short8*)(smem +
                     ((qw * 64 + 32 + l) * 16 + ((2 * dk + hh) ^ sw)) * 16);
        qa0 = MFMA32(wa, xf0, qa0);
        qa1 = MFMA32(wa, xf1, qa1);
      }
      regs_to_bfrags(qa0, hh, qf[2 * et][0], qf[2 * et + 1][0]);
      regs_to_bfrags(qa1, hh, qf[2 * et][1], qf[2 * et + 1][1]);
    }
  }

  float16v Tacc[4][2];  // T^T[d][q] partial over this wave's (kw) keys
#pragma unroll
  for (int dt = 0; dt < 4; dt++) { Tacc[dt][0] = (float16v)0.0f; Tacc[dt][1] = (float16v)0.0f; }
  float lsum[2] = {0.0f, 0.0f};

  for (int kt = 0; kt < N / 128; kt++) {
    const int k0 = kt * 128;
    __syncthreads();
#pragma unroll
    for (int i = 0; i < 8; i++) {
      int r = wave * 32 + i * 4 + lh;
      int us = lu ^ (r & 15);
      load_lds16(XbB + (size_t)(k0 + r) * 256 + us * 16, smem + (wave * 8 + i) * 1024);
      load_lds16(XbTB + (size_t)r * 4096 + (size_t)k0 * 2 + us * 16,
                 smem + 32768 + (wave * 8 + i) * 1024);
    }
    __syncthreads();

#pragma unroll
    for (int ksub = 0; ksub < 2; ksub++) {
      // S-phase: stream kf one at a time (keeps peak VGPR pressure low).
      float16v s0 = (float16v)0.0f, s1 = (float16v)0.0f;
#pragma unroll
      for (int ks = 0; ks < 8; ks++) {
        short8 kf = *(const short8*)(smem +
                    ((kw * 64 + ksub * 32 + l) * 16 + ((2 * ks + hh) ^ sw)) * 16);
        s0 = MFMA32(kf, qf[ks][0], s0);
        s1 = MFMA32(kf, qf[ks][1], s1);
      }
      short8 pf[2][2];  // [qc][kk]
      regs_to_pfrags(s0, hh, lsum[0], pf[0][0], pf[0][1]);
      regs_to_pfrags(s1, hh, lsum[1], pf[1][0], pf[1][1]);
      // T^T += X_tile^T @ P^T  (A from XsT [d][k] tile, B = pf)
#pragma unroll
      for (int kk = 0; kk < 2; kk++)
#pragma unroll
        for (int dt = 0; dt < 4; dt++) {
          short8 xt = *(const short8*)(smem + 32768 +
                      ((dt * 32 + l) * 16 + ((kw * 8 + ksub * 4 + kk * 2 + hh) ^ sw)) * 16);
          Tacc[dt][0] = MFMA32(xt, pf[0][kk], Tacc[dt][0]);
          Tacc[dt][1] = MFMA32(xt, pf[1][kk], Tacc[dt][1]);
        }
    }
  }

  // ---- lsum reduction + Vt staging
  __syncthreads();
  float* Lred = (float*)smem;  // [2][128] in region0
#pragma unroll
  for (int qc = 0; qc < 2; qc++) {
    float t = lsum[qc] + __shfl_xor(lsum[qc], 32);
    if (hh == 0) Lred[kw * 128 + qw * 64 + qc * 32 + l] = t;
  }
#pragma unroll
  for (int i = 0; i < 8; i++) {
    int r = wave * 32 + i * 4 + lh;
    int us = lu ^ (r & 15);
    load_lds16(VtB + (size_t)r * 256 + us * 16, smem + 32768 + (wave * 8 + i) * 1024);
  }
  __syncthreads();
  float inv[2];
#pragma unroll
  for (int qc = 0; qc < 2; qc++) {
    int q = qw * 64 + qc * 32 + l;
    inv[qc] = 1.0f / (Lred[q] + Lred[128 + q]);
  }

  // ---- epilogue GEMM: out^T[e][q] = V^T[e][d] @ T^T[d][q]
  short8 tb[2][8];
#pragma unroll
  for (int qc = 0; qc < 2; qc++)
#pragma unroll
    for (int dt = 0; dt < 4; dt++)
      regs_to_bfrags(Tacc[dt][qc], hh, tb[qc][2 * dt], tb[qc][2 * dt + 1]);

  float16v oacc[4][2];
#pragma unroll
  for (int et = 0; et < 4; et++) { oacc[et][0] = (float16v)0.0f; oacc[et][1] = (float16v)0.0f; }
#pragma unroll
  for (int et = 0; et < 4; et++)
#pragma unroll
    for (int dk = 0; dk < 8; dk++) {
      short8 va = *(const short8*)(smem + 32768 +
                  ((et * 32 + l) * 16 + ((2 * dk + hh) ^ sw)) * 16);
      oacc[et][0] = MFMA32(va, tb[0][dk], oacc[et][0]);
      oacc[et][1] = MFMA32(va, tb[1][dk], oacc[et][1]);
    }
  __syncthreads();  // Vt + Lred consumed; smem becomes Ls [128 q][32 fp32x4 units]

#pragma unroll
  for (int pass = 0; pass < 2; pass++) {
    if (kw == pass) {
#pragma unroll
      for (int et = 0; et < 4; et++)
#pragma unroll
        for (int qc = 0; qc < 2; qc++) {
          int q = qw * 64 + qc * 32 + l;
#pragma unroll
          for (int g = 0; g < 4; g++) {
            int u = (et * 8 + 2 * g + hh) ^ (q & 15);
            float4v* p = (float4v*)(smem + (size_t)q * 512 + u * 16);
            float4v v;
            v.x = oacc[et][qc][4 * g + 0] * inv[qc];
            v.y = oacc[et][qc][4 * g + 1] * inv[qc];
            v.z = oacc[et][qc][4 * g + 2] * inv[qc];
            v.w = oacc[et][qc][4 * g + 3] * inv[qc];
            if (pass == 0) *p = v;
            else { float4v o = *p; o.x += v.x; o.y += v.y; o.z += v.z; o.w += v.w; *p = o; }
          }
        }
    }
    __syncthreads();
  }
#pragma unroll
  for (int i = 0; i < 16; i++) {
    int s = i * 256 + tid;
    int q = s >> 5, up = s & 31, u = up ^ (q & 15);
    float4v v = *(const float4v*)(smem + (size_t)q * 512 + up * 16);
    float* dst = out + (size_t)(q0 + q) * D + u * 4;
    atomicAdd(dst + 0, v.x);
    atomicAdd(dst + 1, v.y);
    atomicAdd(dst + 2, v.z);
    atomicAdd(dst + 3, v.w);
  }
}

extern "C" void kernel_launch(void* const* d_in, const int* in_sizes, int n_in,
                              void* d_out, int out_size, void* d_ws, size_t ws_size,
                              hipStream_t stream) {
  const float* X = (const float*)d_in[0];
  const float* W = (const float*)d_in[1];
  const float* V = (const float*)d_in[2];
  float* out = (float*)d_out;

  unsigned short* Xb = (unsigned short*)d_ws;     // N*D
  unsigned short* XbT = Xb + (size_t)N * D;       // D*N
  unsigned short* Wt = XbT + (size_t)N * D;       // H*D*D (scaled, transposed)
  unsigned short* Vt = Wt + (size_t)H * D * D;    // H*D*D (transposed)

  (void)hipMemsetAsync(d_out, 0, (size_t)N * D * sizeof(float), stream);

  xconv_kernel<<<dim3(N / 128), 256, 0, stream>>>(X, Xb, XbT);
  wvconv_kernel<<<dim3(2 * H), 256, 0, stream>>>(W, V, Wt, Vt);
  attn_kernel<<<dim3((N / 128) * H), 256, 0, stream>>>(Xb, XbT, Wt, Vt, out);
}

// Round 7
// 234.693 us; speedup vs baseline: 2.3564x; 1.5991x over previous
//
#include <hip/hip_runtime.h>
#include <hip/hip_bf16.h>
#include <stdint.h>

#define N 2048
#define D 128
#define H 40

typedef __attribute__((ext_vector_type(8))) short short8;
typedef __attribute__((ext_vector_type(4))) float float4v;
typedef __attribute__((ext_vector_type(16))) float float16v;

static __device__ __forceinline__ unsigned short f32_to_bf16(float f) {
  unsigned int u = __builtin_bit_cast(unsigned int, f);
  unsigned int rounding = 0x7FFFu + ((u >> 16) & 1u);
  return (unsigned short)((u + rounding) >> 16);
}

static __device__ __forceinline__ unsigned int pk2(float lo, float hi) {
  return (unsigned int)f32_to_bf16(lo) | ((unsigned int)f32_to_bf16(hi) << 16);
}

static __device__ __forceinline__ unsigned long long pack4(float x0, float x1,
                                                           float x2, float x3) {
  return (unsigned long long)pk2(x0, x1) | ((unsigned long long)pk2(x2, x3) << 32);
}

// Async global->LDS DMA, 16B/lane. LDS dest = wave-uniform base (+ lane*16 by HW).
static __device__ __forceinline__ void load_lds16(const void* g, void* l) {
  __builtin_amdgcn_global_load_lds(
      (const __attribute__((address_space(1))) unsigned int*)g,
      (__attribute__((address_space(3))) unsigned int*)l, 16, 0, 0);
}

#define MFMA32(a, b, c) __builtin_amdgcn_mfma_f32_32x32x16_bf16((a), (b), (c), 0, 0, 0)

// 32x32 C-layout regs (m=(r&3)+8*(r>>2)+4*hh, col=l) -> two B-fragments
// (k=hh*8+j): f0 = m 0..15, f1 = m 16..31. (Verified R3-R6.)
static __device__ __forceinline__ void regs_to_bfrags(const float16v c, int hh,
                                                      short8& f0, short8& f1) {
  unsigned int a0 = pk2(c[0], c[1]),   a1 = pk2(c[2], c[3]);
  unsigned int a2 = pk2(c[4], c[5]),   a3 = pk2(c[6], c[7]);
  unsigned int a4 = pk2(c[8], c[9]),   a5 = pk2(c[10], c[11]);
  unsigned int a6 = pk2(c[12], c[13]), a7 = pk2(c[14], c[15]);
  unsigned int x0 = __shfl_xor(hh ? a0 : a2, 32);
  unsigned int x1 = __shfl_xor(hh ? a1 : a3, 32);
  unsigned int x2 = __shfl_xor(hh ? a4 : a6, 32);
  unsigned int x3 = __shfl_xor(hh ? a5 : a7, 32);
  uint4 u0 = {hh ? x0 : a0, hh ? x1 : a1, hh ? a2 : x0, hh ? a3 : x1};
  uint4 u1 = {hh ? x2 : a4, hh ? x3 : a5, hh ? a6 : x2, hh ? a7 : x3};
  f0 = __builtin_bit_cast(short8, u0);
  f1 = __builtin_bit_cast(short8, u1);
}

// Same, but exp() first and accumulate the row-sum (softmax denominator).
static __device__ __forceinline__ void regs_to_pfrags(const float16v s, int hh,
                                                      float& lsum, short8& f0,
                                                      short8& f1) {
  float e[16];
  float acc = 0.0f;
#pragma unroll
  for (int i = 0; i < 16; i++) { e[i] = __expf(s[i]); acc += e[i]; }
  lsum += acc;
  unsigned int a0 = pk2(e[0], e[1]),   a1 = pk2(e[2], e[3]);
  unsigned int a2 = pk2(e[4], e[5]),   a3 = pk2(e[6], e[7]);
  unsigned int a4 = pk2(e[8], e[9]),   a5 = pk2(e[10], e[11]);
  unsigned int a6 = pk2(e[12], e[13]), a7 = pk2(e[14], e[15]);
  unsigned int x0 = __shfl_xor(hh ? a0 : a2, 32);
  unsigned int x1 = __shfl_xor(hh ? a1 : a3, 32);
  unsigned int x2 = __shfl_xor(hh ? a4 : a6, 32);
  unsigned int x3 = __shfl_xor(hh ? a5 : a7, 32);
  uint4 u0 = {hh ? x0 : a0, hh ? x1 : a1, hh ? a2 : x0, hh ? a3 : x1};
  uint4 u1 = {hh ? x2 : a4, hh ? x3 : a5, hh ? a6 : x2, hh ? a7 : x3};
  f0 = __builtin_bit_cast(short8, u0);
  f1 = __builtin_bit_cast(short8, u1);
}

// ---- staging helpers ----
// 64 logical rows x 256 B, 16-unit XOR swizzle ^(row&15). 4 DMA instr/wave.
static __device__ __forceinline__ void stage_64x256(const char* gbase, size_t stride,
                                                    int colOff, char* lds, int wave,
                                                    int lane) {
#pragma unroll
  for (int i = 0; i < 4; i++) {
    int r = wave * 16 + i * 4 + (lane >> 4);
    int us = (lane & 15) ^ (r & 15);
    load_lds16(gbase + (size_t)r * stride + colOff + us * 16,
               lds + (wave * 16 + i * 4) * 256);
  }
}
// 128 logical rows x 256 B (32 KB). 8 DMA instr/wave.
static __device__ __forceinline__ void stage_128x256(const char* gbase, size_t stride,
                                                     char* lds, int wave, int lane) {
#pragma unroll
  for (int i = 0; i < 8; i++) {
    int r = wave * 32 + i * 4 + (lane >> 4);
    int us = (lane & 15) ^ (r & 15);
    load_lds16(gbase + (size_t)r * stride + us * 16, lds + (wave * 32 + i * 4) * 256);
  }
}
// 128 logical rows x 128 B -> 64 macro-rows x 256 B, macro-swizzled. 4 instr/wave.
// LDS (m, p): u = p^(m&15); holds global row 2m+(u>>3), bytes (u&7)*16 of the row.
static __device__ __forceinline__ void stage_128x128(const char* gbase, size_t stride,
                                                     int colOff, char* lds, int wave,
                                                     int lane) {
#pragma unroll
  for (int i = 0; i < 4; i++) {
    int m = wave * 16 + i * 4 + (lane >> 4);
    int u = (lane & 15) ^ (m & 15);
    int grow = 2 * m + (u >> 3);
    load_lds16(gbase + (size_t)grow * stride + colOff + (u & 7) * 16,
               lds + (wave * 16 + i * 4) * 256);
  }
}
// read 16B frag (row, kunit in [0,8)) from a macro-swizzled 128x128B tile.
static __device__ __forceinline__ short8 read_macro(const char* lds, int row, int kunit) {
  int m = row >> 1;
  int u = ((row & 1) << 3) | kunit;
  return *(const short8*)(lds + m * 256 + ((u ^ (m & 15)) * 16));
}

// ---- X fp32 -> Xb [n][d] bf16 and XbT [d][n] bf16 ----
__global__ __launch_bounds__(256)
void xconv_kernel(const float* __restrict__ X, unsigned short* __restrict__ Xb,
                  unsigned short* __restrict__ XbT) {
  const int n0 = blockIdx.x * 128;
  const int tid = threadIdx.x;
  __shared__ __align__(16) unsigned short Lt[128 * 136];
  for (int i = tid; i < 128 * 32; i += 256) {
    int row = i >> 5, c4 = (i & 31) * 4;
    float4v x = *(const float4v*)(X + (size_t)(n0 + row) * D + c4);
    unsigned long long p = pack4(x.x, x.y, x.z, x.w);
    *(unsigned long long*)(Lt + row * 136 + c4) = p;
    *(unsigned long long*)(Xb + (size_t)(n0 + row) * D + c4) = p;
  }
  __syncthreads();
  for (int i = tid; i < 128 * 16; i += 256) {
    int d = i >> 4, g = i & 15;
    short8 v;
#pragma unroll
    for (int j = 0; j < 8; j++) v[j] = (short)Lt[(g * 8 + j) * 136 + d];
    *(short8*)(XbT + (size_t)d * N + n0 + g * 8) = v;
  }
}

// ---- W/V fp32 -> bf16 transposed: Wt[h][e][d] (W pre-scaled by 1/sqrt(D)) ----
__global__ __launch_bounds__(256)
void wvconv_kernel(const float* __restrict__ W, const float* __restrict__ V,
                   unsigned short* __restrict__ Wt, unsigned short* __restrict__ Vt) {
  const int b = blockIdx.x;
  const int mat = (b >= H) ? 1 : 0;
  const int h = mat ? b - H : b;
  const float* src = (mat ? V : W) + (size_t)h * D * D;
  unsigned short* dst = (mat ? Vt : Wt) + (size_t)h * D * D;
  const float scale = mat ? 1.0f : 0.08838834764831845f;
  const int tid = threadIdx.x;
  __shared__ __align__(16) unsigned short Lt[128 * 136];
  for (int i = tid; i < 128 * 32; i += 256) {
    int d = i >> 5, e4 = (i & 31) * 4;
    float4v w = *(const float4v*)(src + d * D + e4);
    Lt[(e4 + 0) * 136 + d] = f32_to_bf16(w.x * scale);
    Lt[(e4 + 1) * 136 + d] = f32_to_bf16(w.y * scale);
    Lt[(e4 + 2) * 136 + d] = f32_to_bf16(w.z * scale);
    Lt[(e4 + 3) * 136 + d] = f32_to_bf16(w.w * scale);
  }
  __syncthreads();
  for (int i = tid; i < 128 * 16; i += 256) {
    int e = i >> 4, u = i & 15;
    *(uint4*)((char*)dst + (size_t)e * 256 + u * 16) =
        *(const uint4*)((const char*)Lt + (size_t)e * 272 + u * 16);
  }
}

// ---- attention: per wave 32 q x full k; T = P@X in regs; partials out ----
__global__ __launch_bounds__(256)
void attn_kernel(const unsigned short* __restrict__ Xb,
                 const unsigned short* __restrict__ XbT,
                 const unsigned short* __restrict__ Wt,
                 const unsigned short* __restrict__ Vt,
                 float* __restrict__ Opart) {
  __shared__ __align__(16) char smem[32768];
  const int bx = blockIdx.x;
  const int h = bx >> 4;
  const int q0 = (bx & 15) << 7;
  const int tid = threadIdx.x;
  const int wave = tid >> 6, lane = tid & 63;
  const int l = lane & 31, hh = lane >> 5;

  const char* XbB = (const char*)Xb;
  const char* XbTB = (const char*)XbT;
  const char* WtB = (const char*)(Wt + (size_t)h * D * D);
  const char* VtB = (const char*)(Vt + (size_t)h * D * D);

  // ---- prologue: Q^T[e][q] frags for this wave's 32 q, in 2 d-halves
  float16v qa[4];
#pragma unroll
  for (int et = 0; et < 4; et++) qa[et] = (float16v)0.0f;
#pragma unroll
  for (int dh = 0; dh < 2; dh++) {
    __syncthreads();
    stage_128x128(XbB + (size_t)q0 * 256, 256, dh * 128, smem, wave, lane);
    stage_128x128(WtB, 256, dh * 128, smem + 16384, wave, lane);
    __syncthreads();
    short8 xfr[4];
#pragma unroll
    for (int dk = 0; dk < 4; dk++)
      xfr[dk] = read_macro(smem, wave * 32 + l, dk * 2 + hh);
#pragma unroll
    for (int et = 0; et < 4; et++)
#pragma unroll
      for (int dk = 0; dk < 4; dk++) {
        short8 wa = read_macro(smem + 16384, et * 32 + l, dk * 2 + hh);
        qa[et] = MFMA32(wa, xfr[dk], qa[et]);
      }
  }
  short8 qf[8];
#pragma unroll
  for (int et = 0; et < 4; et++)
    regs_to_bfrags(qa[et], hh, qf[2 * et], qf[2 * et + 1]);

  float16v Tacc[4];
#pragma unroll
  for (int dt = 0; dt < 4; dt++) Tacc[dt] = (float16v)0.0f;
  float lsum = 0.0f;

  // ---- main loop: 64-key tiles
  for (int kt = 0; kt < N / 64; kt++) {
    const int k0 = kt * 64;
    __syncthreads();
    stage_64x256(XbB + (size_t)k0 * 256, 256, 0, smem, wave, lane);
    stage_128x128(XbTB, 4096, k0 * 2, smem + 16384, wave, lane);
    __syncthreads();
#pragma unroll
    for (int ksub = 0; ksub < 2; ksub++) {
      float16v s = (float16v)0.0f;
      const int krow = ksub * 32 + l;
#pragma unroll
      for (int ks = 0; ks < 8; ks++) {
        short8 kf = *(const short8*)(smem + krow * 256 +
                                     (((2 * ks + hh) ^ (krow & 15)) * 16));
        s = MFMA32(kf, qf[ks], s);
      }
      short8 pf0, pf1;
      regs_to_pfrags(s, hh, lsum, pf0, pf1);
#pragma unroll
      for (int kk = 0; kk < 2; kk++) {
        short8 pf = kk ? pf1 : pf0;
#pragma unroll
        for (int dt = 0; dt < 4; dt++) {
          short8 xt = read_macro(smem + 16384, dt * 32 + l, ksub * 4 + kk * 2 + hh);
          Tacc[dt] = MFMA32(xt, pf, Tacc[dt]);
        }
      }
    }
  }

  float tot = lsum + __shfl_xor(lsum, 32);
  float inv = 1.0f / tot;

  // ---- epilogue: out^T[e][q] = V^T[e][d] @ T^T[d][q]
  short8 tb[8];
#pragma unroll
  for (int dt = 0; dt < 4; dt++)
    regs_to_bfrags(Tacc[dt], hh, tb[2 * dt], tb[2 * dt + 1]);

  __syncthreads();
  stage_128x256(VtB, 256, smem, wave, lane);
  __syncthreads();

  float16v oacc[4];
#pragma unroll
  for (int et = 0; et < 4; et++) oacc[et] = (float16v)0.0f;
#pragma unroll
  for (int et = 0; et < 4; et++) {
    const int erow = et * 32 + l;
#pragma unroll
    for (int dk = 0; dk < 8; dk++) {
      short8 va = *(const short8*)(smem + erow * 256 +
                                   (((2 * dk + hh) ^ (erow & 15)) * 16));
      oacc[et] = MFMA32(va, tb[dk], oacc[et]);
    }
  }

  // ---- write per-head partial (no atomics), 2 passes of [128q][64e] fp32
  float* Oph = Opart + (size_t)h * N * D;
#pragma unroll
  for (int pass = 0; pass < 2; pass++) {
    __syncthreads();
    const int qrow = wave * 32 + l;
#pragma unroll
    for (int etL = 0; etL < 2; etL++) {
      int et = pass * 2 + etL;
#pragma unroll
      for (int g = 0; g < 4; g++) {
        int unit = etL * 8 + 2 * g + hh;
        float4v v;
        v.x = oacc[et][4 * g + 0] * inv;
        v.y = oacc[et][4 * g + 1] * inv;
        v.z = oacc[et][4 * g + 2] * inv;
        v.w = oacc[et][4 * g + 3] * inv;
        *(float4v*)(smem + qrow * 256 + ((unit ^ (qrow & 15)) * 16)) = v;
      }
    }
    __syncthreads();
#pragma unroll
    for (int i = 0; i < 8; i++) {
      int idx = i * 256 + tid;
      int qr = idx >> 4, up = idx & 15, u = up ^ (qr & 15);
      float4v v = *(const float4v*)(smem + qr * 256 + up * 16);
      *(float4v*)(Oph + (size_t)(q0 + qr) * D + pass * 64 + u * 4) = v;
    }
  }
}

// ---- reduce over heads: out[i] = sum_h Opart[h][i] ----
__global__ __launch_bounds__(256)
void reduce_kernel(const float* __restrict__ Opart, float* __restrict__ out) {
  int i = blockIdx.x * 256 + threadIdx.x;  // float4 index, 65536 total
  const float4v* p = (const float4v*)Opart + i;
  float4v acc = (float4v)0.0f;
#pragma unroll 8
  for (int h = 0; h < H; h++) acc += p[(size_t)h * (N * D / 4)];
  ((float4v*)out)[i] = acc;
}

extern "C" void kernel_launch(void* const* d_in, const int* in_sizes, int n_in,
                              void* d_out, int out_size, void* d_ws, size_t ws_size,
                              hipStream_t stream) {
  const float* X = (const float*)d_in[0];
  const float* W = (const float*)d_in[1];
  const float* V = (const float*)d_in[2];
  float* out = (float*)d_out;

  unsigned short* Xb = (unsigned short*)d_ws;      // N*D bf16
  unsigned short* XbT = Xb + (size_t)N * D;        // D*N bf16
  unsigned short* Wt = XbT + (size_t)N * D;        // H*D*D bf16 (scaled)
  unsigned short* Vt = Wt + (size_t)H * D * D;     // H*D*D bf16
  float* Opart = (float*)(Vt + (size_t)H * D * D); // H*N*D fp32 (40 MB)

  xconv_kernel<<<dim3(N / 128), 256, 0, stream>>>(X, Xb, XbT);
  wvconv_kernel<<<dim3(2 * H), 256, 0, stream>>>(W, V, Wt, Vt);
  attn_kernel<<<dim3((N / 128) * H), 256, 0, stream>>>(Xb, XbT, Wt, Vt, Opart);
  reduce_kernel<<<dim3(N * D / 4 / 256), 256, 0, stream>>>(Opart, out);
}

// Round 8
// 224.422 us; speedup vs baseline: 2.4643x; 1.0458x over previous
//
#include <hip/hip_runtime.h>
#include <hip/hip_bf16.h>
#include <stdint.h>

#define N 2048
#define D 128
#define H 40

typedef __attribute__((ext_vector_type(8))) short short8;
typedef __attribute__((ext_vector_type(4))) float float4v;
typedef __attribute__((ext_vector_type(8))) float float8v;
typedef __attribute__((ext_vector_type(16))) float float16v;
typedef __attribute__((ext_vector_type(8))) _Float16 half8v;

static __device__ __forceinline__ unsigned short f32_to_bf16(float f) {
  unsigned int u = __builtin_bit_cast(unsigned int, f);
  unsigned int rounding = 0x7FFFu + ((u >> 16) & 1u);
  return (unsigned short)((u + rounding) >> 16);
}

// RNE pack (input conversion paths).
static __device__ __forceinline__ unsigned int pk2(float lo, float hi) {
  return (unsigned int)f32_to_bf16(lo) | ((unsigned int)f32_to_bf16(hi) << 16);
}

// Fast pack: round-half-up + v_perm_b32 byte gather. 3 VALU vs 9. Error bound
// 0.5 ulp (same as RNE, tiny bias) — hot-path only.
static __device__ __forceinline__ unsigned int pk2f(float lo, float hi) {
  unsigned int a = __builtin_bit_cast(unsigned int, lo) + 0x8000u;
  unsigned int b = __builtin_bit_cast(unsigned int, hi) + 0x8000u;
  return __builtin_amdgcn_perm(b, a, 0x07060302u);
}

static __device__ __forceinline__ unsigned long long pack4(float x0, float x1,
                                                           float x2, float x3) {
  return (unsigned long long)pk2(x0, x1) | ((unsigned long long)pk2(x2, x3) << 32);
}

static __device__ __forceinline__ float fast_exp2(float x) {
#if __has_builtin(__builtin_amdgcn_exp2f)
  return __builtin_amdgcn_exp2f(x);
#else
  return __expf(0.69314718056f * x);  // exp2(x) = exp(x*ln2)
#endif
}

// Async global->LDS DMA, 16B/lane. LDS dest = wave-uniform base (+ lane*16 by HW).
static __device__ __forceinline__ void load_lds16(const void* g, void* l) {
  __builtin_amdgcn_global_load_lds(
      (const __attribute__((address_space(1))) unsigned int*)g,
      (__attribute__((address_space(3))) unsigned int*)l, 16, 0, 0);
}

#define MFMA32(a, b, c) __builtin_amdgcn_mfma_f32_32x32x16_bf16((a), (b), (c), 0, 0, 0)

// 32x32 C-layout regs (m=(r&3)+8*(r>>2)+4*hh, col=l) -> two B-fragments
// (k=hh*8+j): f0 = m 0..15, f1 = m 16..31. (Verified R3-R7.)
static __device__ __forceinline__ void regs_to_bfrags(const float16v c, int hh,
                                                      short8& f0, short8& f1) {
  unsigned int a0 = pk2f(c[0], c[1]),   a1 = pk2f(c[2], c[3]);
  unsigned int a2 = pk2f(c[4], c[5]),   a3 = pk2f(c[6], c[7]);
  unsigned int a4 = pk2f(c[8], c[9]),   a5 = pk2f(c[10], c[11]);
  unsigned int a6 = pk2f(c[12], c[13]), a7 = pk2f(c[14], c[15]);
  unsigned int x0 = __shfl_xor(hh ? a0 : a2, 32);
  unsigned int x1 = __shfl_xor(hh ? a1 : a3, 32);
  unsigned int x2 = __shfl_xor(hh ? a4 : a6, 32);
  unsigned int x3 = __shfl_xor(hh ? a5 : a7, 32);
  uint4 u0 = {hh ? x0 : a0, hh ? x1 : a1, hh ? a2 : x0, hh ? a3 : x1};
  uint4 u1 = {hh ? x2 : a4, hh ? x3 : a5, hh ? a6 : x2, hh ? a7 : x3};
  f0 = __builtin_bit_cast(short8, u0);
  f1 = __builtin_bit_cast(short8, u1);
}

// exp2 first (scores pre-scaled by log2e), accumulate row-sum, then pack.
static __device__ __forceinline__ void regs_to_pfrags(const float16v s, int hh,
                                                      float& lsum, short8& f0,
                                                      short8& f1) {
  float e[16];
  float acc = 0.0f;
#pragma unroll
  for (int i = 0; i < 16; i++) { e[i] = fast_exp2(s[i]); acc += e[i]; }
  lsum += acc;
  unsigned int a0 = pk2f(e[0], e[1]),   a1 = pk2f(e[2], e[3]);
  unsigned int a2 = pk2f(e[4], e[5]),   a3 = pk2f(e[6], e[7]);
  unsigned int a4 = pk2f(e[8], e[9]),   a5 = pk2f(e[10], e[11]);
  unsigned int a6 = pk2f(e[12], e[13]), a7 = pk2f(e[14], e[15]);
  unsigned int x0 = __shfl_xor(hh ? a0 : a2, 32);
  unsigned int x1 = __shfl_xor(hh ? a1 : a3, 32);
  unsigned int x2 = __shfl_xor(hh ? a4 : a6, 32);
  unsigned int x3 = __shfl_xor(hh ? a5 : a7, 32);
  uint4 u0 = {hh ? x0 : a0, hh ? x1 : a1, hh ? a2 : x0, hh ? a3 : x1};
  uint4 u1 = {hh ? x2 : a4, hh ? x3 : a5, hh ? a6 : x2, hh ? a7 : x3};
  f0 = __builtin_bit_cast(short8, u0);
  f1 = __builtin_bit_cast(short8, u1);
}

// ---- staging helpers (verified R7) ----
static __device__ __forceinline__ void stage_64x256(const char* gbase, size_t stride,
                                                    int colOff, char* lds, int wave,
                                                    int lane) {
#pragma unroll
  for (int i = 0; i < 4; i++) {
    int r = wave * 16 + i * 4 + (lane >> 4);
    int us = (lane & 15) ^ (r & 15);
    load_lds16(gbase + (size_t)r * stride + colOff + us * 16,
               lds + (wave * 16 + i * 4) * 256);
  }
}
static __device__ __forceinline__ void stage_128x256(const char* gbase, size_t stride,
                                                     char* lds, int wave, int lane) {
#pragma unroll
  for (int i = 0; i < 8; i++) {
    int r = wave * 32 + i * 4 + (lane >> 4);
    int us = (lane & 15) ^ (r & 15);
    load_lds16(gbase + (size_t)r * stride + us * 16, lds + (wave * 32 + i * 4) * 256);
  }
}
// 128 rows x 128 B -> 64 macro-rows x 256 B, macro-swizzled.
static __device__ __forceinline__ void stage_128x128(const char* gbase, size_t stride,
                                                     int colOff, char* lds, int wave,
                                                     int lane) {
#pragma unroll
  for (int i = 0; i < 4; i++) {
    int m = wave * 16 + i * 4 + (lane >> 4);
    int u = (lane & 15) ^ (m & 15);
    int grow = 2 * m + (u >> 3);
    load_lds16(gbase + (size_t)grow * stride + colOff + (u & 7) * 16,
               lds + (wave * 16 + i * 4) * 256);
  }
}
static __device__ __forceinline__ short8 read_macro(const char* lds, int row, int kunit) {
  int m = row >> 1;
  int u = ((row & 1) << 3) | kunit;
  return *(const short8*)(lds + m * 256 + ((u ^ (m & 15)) * 16));
}

// ---- X fp32 -> Xb [n][d] bf16 and XbT [d][n] bf16 ----
__global__ __launch_bounds__(256)
void xconv_kernel(const float* __restrict__ X, unsigned short* __restrict__ Xb,
                  unsigned short* __restrict__ XbT) {
  const int n0 = blockIdx.x * 128;
  const int tid = threadIdx.x;
  __shared__ __align__(16) unsigned short Lt[128 * 136];
  for (int i = tid; i < 128 * 32; i += 256) {
    int row = i >> 5, c4 = (i & 31) * 4;
    float4v x = *(const float4v*)(X + (size_t)(n0 + row) * D + c4);
    unsigned long long p = pack4(x.x, x.y, x.z, x.w);
    *(unsigned long long*)(Lt + row * 136 + c4) = p;
    *(unsigned long long*)(Xb + (size_t)(n0 + row) * D + c4) = p;
  }
  __syncthreads();
  for (int i = tid; i < 128 * 16; i += 256) {
    int d = i >> 4, g = i & 15;
    short8 v;
#pragma unroll
    for (int j = 0; j < 8; j++) v[j] = (short)Lt[(g * 8 + j) * 136 + d];
    *(short8*)(XbT + (size_t)d * N + n0 + g * 8) = v;
  }
}

// ---- W/V -> bf16 transposed. W pre-scaled by log2(e)/sqrt(D) (exp2 softmax) ----
__global__ __launch_bounds__(256)
void wvconv_kernel(const float* __restrict__ W, const float* __restrict__ V,
                   unsigned short* __restrict__ Wt, unsigned short* __restrict__ Vt) {
  const int b = blockIdx.x;
  const int mat = (b >= H) ? 1 : 0;
  const int h = mat ? b - H : b;
  const float* src = (mat ? V : W) + (size_t)h * D * D;
  unsigned short* dst = (mat ? Vt : Wt) + (size_t)h * D * D;
  const float scale = mat ? 1.0f : 0.1275174313f;  // log2(e)/sqrt(128)
  const int tid = threadIdx.x;
  __shared__ __align__(16) unsigned short Lt[128 * 136];
  for (int i = tid; i < 128 * 32; i += 256) {
    int d = i >> 5, e4 = (i & 31) * 4;
    float4v w = *(const float4v*)(src + d * D + e4);
    Lt[(e4 + 0) * 136 + d] = f32_to_bf16(w.x * scale);
    Lt[(e4 + 1) * 136 + d] = f32_to_bf16(w.y * scale);
    Lt[(e4 + 2) * 136 + d] = f32_to_bf16(w.z * scale);
    Lt[(e4 + 3) * 136 + d] = f32_to_bf16(w.w * scale);
  }
  __syncthreads();
  for (int i = tid; i < 128 * 16; i += 256) {
    int e = i >> 4, u = i & 15;
    *(uint4*)((char*)dst + (size_t)e * 256 + u * 16) =
        *(const uint4*)((const char*)Lt + (size_t)e * 272 + u * 16);
  }
}

// ---- attention: split-k. Block = (head, q-tile, k-half); wave = 32 q x 1024 k.
// Writes UNNORMALIZED O partial (fp16) + row lsum; reduce_kernel normalizes.
__global__ __launch_bounds__(256)
void attn_kernel(const unsigned short* __restrict__ Xb,
                 const unsigned short* __restrict__ XbT,
                 const unsigned short* __restrict__ Wt,
                 const unsigned short* __restrict__ Vt,
                 unsigned short* __restrict__ Opart, float* __restrict__ Lsum) {
  __shared__ __align__(16) char smem[32768];
  const int bx = blockIdx.x;
  const int kh = bx & 1;
  const int q0 = ((bx >> 1) & 15) << 7;
  const int h = bx >> 5;
  const int tid = threadIdx.x;
  const int wave = tid >> 6, lane = tid & 63;
  const int l = lane & 31, hh = lane >> 5;

  const char* XbB = (const char*)Xb;
  const char* XbTB = (const char*)XbT;
  const char* WtB = (const char*)(Wt + (size_t)h * D * D);
  const char* VtB = (const char*)(Vt + (size_t)h * D * D);

  // ---- prologue: Q^T frags for this wave's 32 q (scores pre-scaled by log2e)
  float16v qa[4];
#pragma unroll
  for (int et = 0; et < 4; et++) qa[et] = (float16v)0.0f;
#pragma unroll
  for (int dh = 0; dh < 2; dh++) {
    __syncthreads();
    stage_128x128(XbB + (size_t)q0 * 256, 256, dh * 128, smem, wave, lane);
    stage_128x128(WtB, 256, dh * 128, smem + 16384, wave, lane);
    __syncthreads();
    short8 xfr[4];
#pragma unroll
    for (int dk = 0; dk < 4; dk++)
      xfr[dk] = read_macro(smem, wave * 32 + l, dk * 2 + hh);
#pragma unroll
    for (int et = 0; et < 4; et++)
#pragma unroll
      for (int dk = 0; dk < 4; dk++) {
        short8 wa = read_macro(smem + 16384, et * 32 + l, dk * 2 + hh);
        qa[et] = MFMA32(wa, xfr[dk], qa[et]);
      }
  }
  short8 qf[8];
#pragma unroll
  for (int et = 0; et < 4; et++)
    regs_to_bfrags(qa[et], hh, qf[2 * et], qf[2 * et + 1]);

  float16v Tacc[4];
#pragma unroll
  for (int dt = 0; dt < 4; dt++) Tacc[dt] = (float16v)0.0f;
  float lsum = 0.0f;

  // ---- main loop: 16 x 64-key tiles over this block's k-half
  const int kbase = kh * (N / 2);
  for (int kt = 0; kt < 16; kt++) {
    const int k0 = kbase + kt * 64;
    __syncthreads();
    stage_64x256(XbB + (size_t)k0 * 256, 256, 0, smem, wave, lane);
    stage_128x128(XbTB, 4096, k0 * 2, smem + 16384, wave, lane);
    __syncthreads();
#pragma unroll
    for (int ksub = 0; ksub < 2; ksub++) {
      // two independent MFMA chains halve the serial S latency
      float16v sa = (float16v)0.0f, sb = (float16v)0.0f;
      const int krow = ksub * 32 + l;
#pragma unroll
      for (int ks = 0; ks < 4; ks++) {
        short8 kfa = *(const short8*)(smem + krow * 256 +
                                      (((2 * ks + hh) ^ (krow & 15)) * 16));
        short8 kfb = *(const short8*)(smem + krow * 256 +
                                      (((2 * (ks + 4) + hh) ^ (krow & 15)) * 16));
        sa = MFMA32(kfa, qf[ks], sa);
        sb = MFMA32(kfb, qf[ks + 4], sb);
      }
      float16v s = sa + sb;
      short8 pf0, pf1;
      regs_to_pfrags(s, hh, lsum, pf0, pf1);
#pragma unroll
      for (int kk = 0; kk < 2; kk++) {
        short8 pf = kk ? pf1 : pf0;
#pragma unroll
        for (int dt = 0; dt < 4; dt++) {
          short8 xt = read_macro(smem + 16384, dt * 32 + l, ksub * 4 + kk * 2 + hh);
          Tacc[dt] = MFMA32(xt, pf, Tacc[dt]);
        }
      }
    }
  }

  // row sums for this k-half (hh halves cover disjoint keys -> add)
  float tot = lsum + __shfl_xor(lsum, 32);
  if (hh == 0) Lsum[(size_t)(h * 2 + kh) * N + q0 + wave * 32 + l] = tot;

  // ---- epilogue: O^T[e][q] = V^T[e][d] @ T^T[d][q]   (unnormalized)
  short8 tb[8];
#pragma unroll
  for (int dt = 0; dt < 4; dt++)
    regs_to_bfrags(Tacc[dt], hh, tb[2 * dt], tb[2 * dt + 1]);

  __syncthreads();
  stage_128x256(VtB, 256, smem, wave, lane);
  __syncthreads();

  float16v oacc[4];
#pragma unroll
  for (int et = 0; et < 4; et++) oacc[et] = (float16v)0.0f;
#pragma unroll
  for (int et = 0; et < 4; et++) {
    const int erow = et * 32 + l;
#pragma unroll
    for (int dk = 0; dk < 8; dk++) {
      short8 va = *(const short8*)(smem + erow * 256 +
                                   (((2 * dk + hh) ^ (erow & 15)) * 16));
      oacc[et] = MFMA32(va, tb[dk], oacc[et]);
    }
  }

  // ---- write per-(head,kh) fp16 partial, LDS-transposed, coalesced 8B stores
  unsigned short* Oph = Opart + (size_t)(h * 2 + kh) * N * D;
#pragma unroll
  for (int pass = 0; pass < 2; pass++) {
    __syncthreads();
    const int qrow = wave * 32 + l;
#pragma unroll
    for (int etL = 0; etL < 2; etL++) {
      int et = pass * 2 + etL;
#pragma unroll
      for (int g = 0; g < 4; g++) {
        int unit = etL * 8 + 2 * g + hh;
        float4v v;
        v.x = oacc[et][4 * g + 0];
        v.y = oacc[et][4 * g + 1];
        v.z = oacc[et][4 * g + 2];
        v.w = oacc[et][4 * g + 3];
        *(float4v*)(smem + qrow * 256 + ((unit ^ (qrow & 15)) * 16)) = v;
      }
    }
    __syncthreads();
#pragma unroll
    for (int i = 0; i < 8; i++) {
      int idx = i * 256 + tid;
      int qr = idx >> 4, up = idx & 15, u = up ^ (qr & 15);
      float4v v = *(const float4v*)(smem + qr * 256 + up * 16);
      auto h0 = __builtin_amdgcn_cvt_pkrtz(v.x, v.y);
      auto h1 = __builtin_amdgcn_cvt_pkrtz(v.z, v.w);
      uint2 st = {__builtin_bit_cast(unsigned int, h0),
                  __builtin_bit_cast(unsigned int, h1)};
      *(uint2*)(Oph + (size_t)(q0 + qr) * D + pass * 64 + u * 4) = st;
    }
  }
}

// ---- reduce: out[n][e] = sum_h (O[h,0]+O[h,1]) / (l[h,0]+l[h,1]) ----
__global__ __launch_bounds__(256)
void reduce_kernel(const unsigned short* __restrict__ Opart,
                   const float* __restrict__ Lsum, float* __restrict__ out) {
  int idx = blockIdx.x * 256 + threadIdx.x;  // 8-float unit, 32768 total
  int n = idx >> 4;
  const uint4* base = (const uint4*)Opart;
  float8v acc = (float8v)0.0f;
#pragma unroll 4
  for (int h = 0; h < H; h++) {
    float lt = Lsum[(size_t)(2 * h) * N + n] + Lsum[(size_t)(2 * h + 1) * N + n];
    float il = __builtin_amdgcn_rcpf(lt);
    uint4 a = base[(size_t)(2 * h) * (N * D / 8) + idx];
    uint4 b = base[(size_t)(2 * h + 1) * (N * D / 8) + idx];
    float8v fa = __builtin_convertvector(__builtin_bit_cast(half8v, a), float8v);
    float8v fb = __builtin_convertvector(__builtin_bit_cast(half8v, b), float8v);
    acc += (fa + fb) * il;
  }
  *(float8v*)(out + (size_t)idx * 8) = acc;
}

extern "C" void kernel_launch(void* const* d_in, const int* in_sizes, int n_in,
                              void* d_out, int out_size, void* d_ws, size_t ws_size,
                              hipStream_t stream) {
  const float* X = (const float*)d_in[0];
  const float* W = (const float*)d_in[1];
  const float* V = (const float*)d_in[2];
  float* out = (float*)d_out;

  unsigned short* Xb = (unsigned short*)d_ws;        // N*D bf16
  unsigned short* XbT = Xb + (size_t)N * D;          // D*N bf16
  unsigned short* Wt = XbT + (size_t)N * D;          // H*D*D bf16 (log2e-scaled)
  unsigned short* Vt = Wt + (size_t)H * D * D;       // H*D*D bf16
  unsigned short* Opart = Vt + (size_t)H * D * D;    // H*2*N*D fp16 (42 MB)
  float* Lsum = (float*)(Opart + (size_t)H * 2 * N * D);  // H*2*N fp32

  xconv_kernel<<<dim3(N / 128), 256, 0, stream>>>(X, Xb, XbT);
  wvconv_kernel<<<dim3(2 * H), 256, 0, stream>>>(W, V, Wt, Vt);
  attn_kernel<<<dim3(16 * 2 * H), 256, 0, stream>>>(Xb, XbT, Wt, Vt, Opart, Lsum);
  reduce_kernel<<<dim3(N * D / 8 / 256), 256, 0, stream>>>(Opart, Lsum, out);
}

// Round 9
// 201.661 us; speedup vs baseline: 2.7424x; 1.1129x over previous
//
#include <hip/hip_runtime.h>
#include <hip/hip_bf16.h>
#include <stdint.h>

#define N 2048
#define D 128
#define H 40
#define NT 16  // 64-key tiles per k-half

typedef __attribute__((ext_vector_type(8))) short short8;
typedef __attribute__((ext_vector_type(4))) float float4v;
typedef __attribute__((ext_vector_type(8))) float float8v;
typedef __attribute__((ext_vector_type(16))) float float16v;
typedef __attribute__((ext_vector_type(8))) _Float16 half8v;

static __device__ __forceinline__ unsigned short f32_to_bf16(float f) {
  unsigned int u = __builtin_bit_cast(unsigned int, f);
  unsigned int rounding = 0x7FFFu + ((u >> 16) & 1u);
  return (unsigned short)((u + rounding) >> 16);
}

static __device__ __forceinline__ unsigned int pk2(float lo, float hi) {
  return (unsigned int)f32_to_bf16(lo) | ((unsigned int)f32_to_bf16(hi) << 16);
}

// Fast pack: round-half-up + v_perm_b32 byte gather (3 VALU). Hot path only.
static __device__ __forceinline__ unsigned int pk2f(float lo, float hi) {
  unsigned int a = __builtin_bit_cast(unsigned int, lo) + 0x8000u;
  unsigned int b = __builtin_bit_cast(unsigned int, hi) + 0x8000u;
  return __builtin_amdgcn_perm(b, a, 0x07060302u);
}

static __device__ __forceinline__ unsigned long long pack4(float x0, float x1,
                                                           float x2, float x3) {
  return (unsigned long long)pk2(x0, x1) | ((unsigned long long)pk2(x2, x3) << 32);
}

static __device__ __forceinline__ float fast_exp2(float x) {
#if __has_builtin(__builtin_amdgcn_exp2f)
  return __builtin_amdgcn_exp2f(x);
#else
  return __expf(0.69314718056f * x);
#endif
}

static __device__ __forceinline__ void load_lds16(const void* g, void* l) {
  __builtin_amdgcn_global_load_lds(
      (const __attribute__((address_space(1))) unsigned int*)g,
      (__attribute__((address_space(3))) unsigned int*)l, 16, 0, 0);
}

#define MFMA32(a, b, c) __builtin_amdgcn_mfma_f32_32x32x16_bf16((a), (b), (c), 0, 0, 0)

// 32x32 C-layout regs (m=(r&3)+8*(r>>2)+4*hh, col=l) -> two B-fragments
// (k=hh*8+j): f0 = m 0..15, f1 = m 16..31. (Verified R3-R8.)
static __device__ __forceinline__ void regs_to_bfrags(const float16v c, int hh,
                                                      short8& f0, short8& f1) {
  unsigned int a0 = pk2f(c[0], c[1]),   a1 = pk2f(c[2], c[3]);
  unsigned int a2 = pk2f(c[4], c[5]),   a3 = pk2f(c[6], c[7]);
  unsigned int a4 = pk2f(c[8], c[9]),   a5 = pk2f(c[10], c[11]);
  unsigned int a6 = pk2f(c[12], c[13]), a7 = pk2f(c[14], c[15]);
  unsigned int x0 = __shfl_xor(hh ? a0 : a2, 32);
  unsigned int x1 = __shfl_xor(hh ? a1 : a3, 32);
  unsigned int x2 = __shfl_xor(hh ? a4 : a6, 32);
  unsigned int x3 = __shfl_xor(hh ? a5 : a7, 32);
  uint4 u0 = {hh ? x0 : a0, hh ? x1 : a1, hh ? a2 : x0, hh ? a3 : x1};
  uint4 u1 = {hh ? x2 : a4, hh ? x3 : a5, hh ? a6 : x2, hh ? a7 : x3};
  f0 = __builtin_bit_cast(short8, u0);
  f1 = __builtin_bit_cast(short8, u1);
}

// exp2 first (scores pre-scaled by log2e), accumulate row-sum, then pack.
static __device__ __forceinline__ void regs_to_pfrags(const float16v s, int hh,
                                                      float& lsum, short8& f0,
                                                      short8& f1) {
  float e[16];
  float acc = 0.0f;
#pragma unroll
  for (int i = 0; i < 16; i++) { e[i] = fast_exp2(s[i]); acc += e[i]; }
  lsum += acc;
  unsigned int a0 = pk2f(e[0], e[1]),   a1 = pk2f(e[2], e[3]);
  unsigned int a2 = pk2f(e[4], e[5]),   a3 = pk2f(e[6], e[7]);
  unsigned int a4 = pk2f(e[8], e[9]),   a5 = pk2f(e[10], e[11]);
  unsigned int a6 = pk2f(e[12], e[13]), a7 = pk2f(e[14], e[15]);
  unsigned int x0 = __shfl_xor(hh ? a0 : a2, 32);
  unsigned int x1 = __shfl_xor(hh ? a1 : a3, 32);
  unsigned int x2 = __shfl_xor(hh ? a4 : a6, 32);
  unsigned int x3 = __shfl_xor(hh ? a5 : a7, 32);
  uint4 u0 = {hh ? x0 : a0, hh ? x1 : a1, hh ? a2 : x0, hh ? a3 : x1};
  uint4 u1 = {hh ? x2 : a4, hh ? x3 : a5, hh ? a6 : x2, hh ? a7 : x3};
  f0 = __builtin_bit_cast(short8, u0);
  f1 = __builtin_bit_cast(short8, u1);
}

// ---- staging helpers (verified R7/R8) ----
static __device__ __forceinline__ void stage_64x256(const char* gbase, size_t stride,
                                                    int colOff, char* lds, int wave,
                                                    int lane) {
#pragma unroll
  for (int i = 0; i < 4; i++) {
    int r = wave * 16 + i * 4 + (lane >> 4);
    int us = (lane & 15) ^ (r & 15);
    load_lds16(gbase + (size_t)r * stride + colOff + us * 16,
               lds + (wave * 16 + i * 4) * 256);
  }
}
static __device__ __forceinline__ void stage_128x256(const char* gbase, size_t stride,
                                                     char* lds, int wave, int lane) {
#pragma unroll
  for (int i = 0; i < 8; i++) {
    int r = wave * 32 + i * 4 + (lane >> 4);
    int us = (lane & 15) ^ (r & 15);
    load_lds16(gbase + (size_t)r * stride + us * 16, lds + (wave * 32 + i * 4) * 256);
  }
}
static __device__ __forceinline__ void stage_128x128(const char* gbase, size_t stride,
                                                     int colOff, char* lds, int wave,
                                                     int lane) {
#pragma unroll
  for (int i = 0; i < 4; i++) {
    int m = wave * 16 + i * 4 + (lane >> 4);
    int u = (lane & 15) ^ (m & 15);
    int grow = 2 * m + (u >> 3);
    load_lds16(gbase + (size_t)grow * stride + colOff + (u & 7) * 16,
               lds + (wave * 16 + i * 4) * 256);
  }
}
static __device__ __forceinline__ short8 read_macro(const char* lds, int row, int kunit) {
  int m = row >> 1;
  int u = ((row & 1) << 3) | kunit;
  return *(const short8*)(lds + m * 256 + ((u ^ (m & 15)) * 16));
}

// ---- X fp32 -> Xb [n][d] bf16 and XbT [d][n] bf16 ----
__global__ __launch_bounds__(256)
void xconv_kernel(const float* __restrict__ X, unsigned short* __restrict__ Xb,
                  unsigned short* __restrict__ XbT) {
  const int n0 = blockIdx.x * 128;
  const int tid = threadIdx.x;
  __shared__ __align__(16) unsigned short Lt[128 * 136];
  for (int i = tid; i < 128 * 32; i += 256) {
    int row = i >> 5, c4 = (i & 31) * 4;
    float4v x = *(const float4v*)(X + (size_t)(n0 + row) * D + c4);
    unsigned long long p = pack4(x.x, x.y, x.z, x.w);
    *(unsigned long long*)(Lt + row * 136 + c4) = p;
    *(unsigned long long*)(Xb + (size_t)(n0 + row) * D + c4) = p;
  }
  __syncthreads();
  for (int i = tid; i < 128 * 16; i += 256) {
    int d = i >> 4, g = i & 15;
    short8 v;
#pragma unroll
    for (int j = 0; j < 8; j++) v[j] = (short)Lt[(g * 8 + j) * 136 + d];
    *(short8*)(XbT + (size_t)d * N + n0 + g * 8) = v;
  }
}

// ---- W/V -> bf16 transposed. W pre-scaled by log2(e)/sqrt(D) ----
__global__ __launch_bounds__(256)
void wvconv_kernel(const float* __restrict__ W, const float* __restrict__ V,
                   unsigned short* __restrict__ Wt, unsigned short* __restrict__ Vt) {
  const int b = blockIdx.x;
  const int mat = (b >= H) ? 1 : 0;
  const int h = mat ? b - H : b;
  const float* src = (mat ? V : W) + (size_t)h * D * D;
  unsigned short* dst = (mat ? Vt : Wt) + (size_t)h * D * D;
  const float scale = mat ? 1.0f : 0.1275174313f;  // log2(e)/sqrt(128)
  const int tid = threadIdx.x;
  __shared__ __align__(16) unsigned short Lt[128 * 136];
  for (int i = tid; i < 128 * 32; i += 256) {
    int d = i >> 5, e4 = (i & 31) * 4;
    float4v w = *(const float4v*)(src + d * D + e4);
    Lt[(e4 + 0) * 136 + d] = f32_to_bf16(w.x * scale);
    Lt[(e4 + 1) * 136 + d] = f32_to_bf16(w.y * scale);
    Lt[(e4 + 2) * 136 + d] = f32_to_bf16(w.z * scale);
    Lt[(e4 + 3) * 136 + d] = f32_to_bf16(w.w * scale);
  }
  __syncthreads();
  for (int i = tid; i < 128 * 16; i += 256) {
    int e = i >> 4, u = i & 15;
    *(uint4*)((char*)dst + (size_t)e * 256 + u * 16) =
        *(const uint4*)((const char*)Lt + (size_t)e * 272 + u * 16);
  }
}

// ---- attention: split-k x2, double-buffered staging, 1 barrier/tile ----
__global__ __launch_bounds__(256)
void attn_kernel(const unsigned short* __restrict__ Xb,
                 const unsigned short* __restrict__ XbT,
                 const unsigned short* __restrict__ Wt,
                 const unsigned short* __restrict__ Vt,
                 unsigned short* __restrict__ Opart, float* __restrict__ Lsum) {
  __shared__ __align__(16) char smem[65536];
  char* buf0 = smem;
  char* buf1 = smem + 32768;
  const int bx = blockIdx.x;
  const int kh = bx & 1;
  const int q0 = ((bx >> 1) & 15) << 7;
  const int h = bx >> 5;
  const int tid = threadIdx.x;
  const int wave = tid >> 6, lane = tid & 63;
  const int l = lane & 31, hh = lane >> 5;

  const char* XbB = (const char*)Xb;
  const char* XbTB = (const char*)XbT;
  const char* WtB = (const char*)(Wt + (size_t)h * D * D);
  const char* VtB = (const char*)(Vt + (size_t)h * D * D);
  const int kbase = kh * (N / 2);

  // ---- prologue: Q^T frags, pipelined across the two d-halves
  stage_128x128(XbB + (size_t)q0 * 256, 256, 0, buf0, wave, lane);
  stage_128x128(WtB, 256, 0, buf0 + 16384, wave, lane);
  __syncthreads();  // buf0 (half0) ready
  stage_128x128(XbB + (size_t)q0 * 256, 256, 128, buf1, wave, lane);
  stage_128x128(WtB, 256, 128, buf1 + 16384, wave, lane);

  float16v qa[4];
#pragma unroll
  for (int et = 0; et < 4; et++) qa[et] = (float16v)0.0f;
  {
    short8 xfr[4];
#pragma unroll
    for (int dk = 0; dk < 4; dk++)
      xfr[dk] = read_macro(buf0, wave * 32 + l, dk * 2 + hh);
#pragma unroll
    for (int et = 0; et < 4; et++)
#pragma unroll
      for (int dk = 0; dk < 4; dk++)
        qa[et] = MFMA32(read_macro(buf0 + 16384, et * 32 + l, dk * 2 + hh),
                        xfr[dk], qa[et]);
  }
  __syncthreads();  // buf1 (half1) ready, buf0 reads done
  stage_64x256(XbB + (size_t)kbase * 256, 256, 0, buf0, wave, lane);
  stage_128x128(XbTB, 4096, kbase * 2, buf0 + 16384, wave, lane);
  {
    short8 xfr[4];
#pragma unroll
    for (int dk = 0; dk < 4; dk++)
      xfr[dk] = read_macro(buf1, wave * 32 + l, dk * 2 + hh);
#pragma unroll
    for (int et = 0; et < 4; et++)
#pragma unroll
      for (int dk = 0; dk < 4; dk++)
        qa[et] = MFMA32(read_macro(buf1 + 16384, et * 32 + l, dk * 2 + hh),
                        xfr[dk], qa[et]);
  }
  short8 qf[8];
#pragma unroll
  for (int et = 0; et < 4; et++)
    regs_to_bfrags(qa[et], hh, qf[2 * et], qf[2 * et + 1]);

  float16v Tacc[4];
#pragma unroll
  for (int dt = 0; dt < 4; dt++) Tacc[dt] = (float16v)0.0f;
  float lsum = 0.0f;
  __syncthreads();  // tile0 ready in buf0, buf1 free

  // ---- main loop: prefetch next tile, compute current, single barrier
  for (int kt = 0; kt < NT; kt++) {
    char* cur = (kt & 1) ? buf1 : buf0;
    char* nxt = (kt & 1) ? buf0 : buf1;
    if (kt + 1 < NT) {
      const int k0n = kbase + (kt + 1) * 64;
      stage_64x256(XbB + (size_t)k0n * 256, 256, 0, nxt, wave, lane);
      stage_128x128(XbTB, 4096, k0n * 2, nxt + 16384, wave, lane);
    } else {
      stage_128x256(VtB, 256, nxt, wave, lane);  // Vt -> buf0 (NT even)
    }
#pragma unroll
    for (int ksub = 0; ksub < 2; ksub++) {
      float16v s = (float16v)0.0f;
      const int krow = ksub * 32 + l;
#pragma unroll
      for (int ks = 0; ks < 8; ks++) {
        short8 kf = *(const short8*)(cur + krow * 256 +
                                     (((2 * ks + hh) ^ (krow & 15)) * 16));
        s = MFMA32(kf, qf[ks], s);
      }
      short8 pf0, pf1;
      regs_to_pfrags(s, hh, lsum, pf0, pf1);
#pragma unroll
      for (int kk = 0; kk < 2; kk++) {
        short8 pf = kk ? pf1 : pf0;
#pragma unroll
        for (int dt = 0; dt < 4; dt++) {
          short8 xt = read_macro(cur + 16384, dt * 32 + l, ksub * 4 + kk * 2 + hh);
          Tacc[dt] = MFMA32(xt, pf, Tacc[dt]);
        }
      }
    }
    __syncthreads();  // next buffer ready; cur reads done for reuse
  }

  float tot = lsum + __shfl_xor(lsum, 32);
  if (hh == 0) Lsum[(size_t)(h * 2 + kh) * N + q0 + wave * 32 + l] = tot;

  // ---- epilogue: O^T[e][q] = V^T[e][d] @ T^T[d][q]  (Vt already in buf0)
  short8 tb[8];
#pragma unroll
  for (int dt = 0; dt < 4; dt++)
    regs_to_bfrags(Tacc[dt], hh, tb[2 * dt], tb[2 * dt + 1]);

  float16v oacc[4];
#pragma unroll
  for (int et = 0; et < 4; et++) oacc[et] = (float16v)0.0f;
#pragma unroll
  for (int et = 0; et < 4; et++) {
    const int erow = et * 32 + l;
#pragma unroll
    for (int dk = 0; dk < 8; dk++) {
      short8 va = *(const short8*)(buf0 + erow * 256 +
                                   (((2 * dk + hh) ^ (erow & 15)) * 16));
      oacc[et] = MFMA32(va, tb[dk], oacc[et]);
    }
  }

  // ---- write per-(head,kh) fp16 partial via buf1 transpose
  unsigned short* Oph = Opart + (size_t)(h * 2 + kh) * N * D;
#pragma unroll
  for (int pass = 0; pass < 2; pass++) {
    __syncthreads();
    const int qrow = wave * 32 + l;
#pragma unroll
    for (int etL = 0; etL < 2; etL++) {
      int et = pass * 2 + etL;
#pragma unroll
      for (int g = 0; g < 4; g++) {
        int unit = etL * 8 + 2 * g + hh;
        float4v v;
        v.x = oacc[et][4 * g + 0];
        v.y = oacc[et][4 * g + 1];
        v.z = oacc[et][4 * g + 2];
        v.w = oacc[et][4 * g + 3];
        *(float4v*)(buf1 + qrow * 256 + ((unit ^ (qrow & 15)) * 16)) = v;
      }
    }
    __syncthreads();
#pragma unroll
    for (int i = 0; i < 8; i++) {
      int idx = i * 256 + tid;
      int qr = idx >> 4, up = idx & 15, u = up ^ (qr & 15);
      float4v v = *(const float4v*)(buf1 + qr * 256 + up * 16);
      auto h0 = __builtin_amdgcn_cvt_pkrtz(v.x, v.y);
      auto h1 = __builtin_amdgcn_cvt_pkrtz(v.z, v.w);
      uint2 st = {__builtin_bit_cast(unsigned int, h0),
                  __builtin_bit_cast(unsigned int, h1)};
      *(uint2*)(Oph + (size_t)(q0 + qr) * D + pass * 64 + u * 4) = st;
    }
  }
}

// ---- reduce: out[n][e] = sum_h (O[h,0]+O[h,1]) / (l[h,0]+l[h,1]) ----
__global__ __launch_bounds__(256)
void reduce_kernel(const unsigned short* __restrict__ Opart,
                   const float* __restrict__ Lsum, float* __restrict__ out) {
  int idx = blockIdx.x * 256 + threadIdx.x;  // 8-float unit, 32768 total
  int n = idx >> 4;
  const uint4* base = (const uint4*)Opart;
  float8v acc = (float8v)0.0f;
#pragma unroll 4
  for (int h = 0; h < H; h++) {
    float lt = Lsum[(size_t)(2 * h) * N + n] + Lsum[(size_t)(2 * h + 1) * N + n];
    float il = __builtin_amdgcn_rcpf(lt);
    uint4 a = base[(size_t)(2 * h) * (N * D / 8) + idx];
    uint4 b = base[(size_t)(2 * h + 1) * (N * D / 8) + idx];
    float8v fa = __builtin_convertvector(__builtin_bit_cast(half8v, a), float8v);
    float8v fb = __builtin_convertvector(__builtin_bit_cast(half8v, b), float8v);
    acc += (fa + fb) * il;
  }
  *(float8v*)(out + (size_t)idx * 8) = acc;
}

extern "C" void kernel_launch(void* const* d_in, const int* in_sizes, int n_in,
                              void* d_out, int out_size, void* d_ws, size_t ws_size,
                              hipStream_t stream) {
  const float* X = (const float*)d_in[0];
  const float* W = (const float*)d_in[1];
  const float* V = (const float*)d_in[2];
  float* out = (float*)d_out;

  unsigned short* Xb = (unsigned short*)d_ws;        // N*D bf16
  unsigned short* XbT = Xb + (size_t)N * D;          // D*N bf16
  unsigned short* Wt = XbT + (size_t)N * D;          // H*D*D bf16 (log2e-scaled)
  unsigned short* Vt = Wt + (size_t)H * D * D;       // H*D*D bf16
  unsigned short* Opart = Vt + (size_t)H * D * D;    // H*2*N*D fp16 (42 MB)
  float* Lsum = (float*)(Opart + (size_t)H * 2 * N * D);  // H*2*N fp32

  xconv_kernel<<<dim3(N / 128), 256, 0, stream>>>(X, Xb, XbT);
  wvconv_kernel<<<dim3(2 * H), 256, 0, stream>>>(W, V, Wt, Vt);
  attn_kernel<<<dim3(16 * 2 * H), 256, 0, stream>>>(Xb, XbT, Wt, Vt, Opart, Lsum);
  reduce_kernel<<<dim3(N * D / 8 / 256), 256, 0, stream>>>(Opart, Lsum, out);
}

// Round 10
// 191.293 us; speedup vs baseline: 2.8911x; 1.0542x over previous
//
#include <hip/hip_runtime.h>
#include <hip/hip_bf16.h>
#include <stdint.h>

#define N 2048
#define D 128
#define H 40
#define NT 16  // 64-key tiles per k-half

typedef __attribute__((ext_vector_type(8))) short short8;
typedef __attribute__((ext_vector_type(4))) float float4v;
typedef __attribute__((ext_vector_type(16))) float float16v;
typedef __attribute__((ext_vector_type(4))) _Float16 half4v;

static __device__ __forceinline__ unsigned short f32_to_bf16(float f) {
  unsigned int u = __builtin_bit_cast(unsigned int, f);
  unsigned int rounding = 0x7FFFu + ((u >> 16) & 1u);
  return (unsigned short)((u + rounding) >> 16);
}

static __device__ __forceinline__ unsigned int pk2(float lo, float hi) {
  return (unsigned int)f32_to_bf16(lo) | ((unsigned int)f32_to_bf16(hi) << 16);
}

// Fast pack: round-half-up + v_perm_b32 byte gather (3 VALU). Hot path only.
static __device__ __forceinline__ unsigned int pk2f(float lo, float hi) {
  unsigned int a = __builtin_bit_cast(unsigned int, lo) + 0x8000u;
  unsigned int b = __builtin_bit_cast(unsigned int, hi) + 0x8000u;
  return __builtin_amdgcn_perm(b, a, 0x07060302u);
}

static __device__ __forceinline__ unsigned long long pack4(float x0, float x1,
                                                           float x2, float x3) {
  return (unsigned long long)pk2(x0, x1) | ((unsigned long long)pk2(x2, x3) << 32);
}

static __device__ __forceinline__ float fast_exp2(float x) {
#if __has_builtin(__builtin_amdgcn_exp2f)
  return __builtin_amdgcn_exp2f(x);
#else
  return __expf(0.69314718056f * x);
#endif
}

static __device__ __forceinline__ float bf2f(unsigned short u) {
  unsigned int x = ((unsigned int)u) << 16;
  return __builtin_bit_cast(float, x);
}

static __device__ __forceinline__ long long mk64(unsigned int lo, unsigned int hi) {
  return (long long)(((unsigned long long)hi << 32) | lo);
}

static __device__ __forceinline__ void load_lds16(const void* g, void* l) {
  __builtin_amdgcn_global_load_lds(
      (const __attribute__((address_space(1))) unsigned int*)g,
      (__attribute__((address_space(3))) unsigned int*)l, 16, 0, 0);
}

#define MFMA32(a, b, c) __builtin_amdgcn_mfma_f32_32x32x16_bf16((a), (b), (c), 0, 0, 0)
#define MFMA8(a, b, c) __builtin_amdgcn_mfma_f32_32x32x16_fp8_fp8((a), (b), (c), 0, 0, 0)

// 32x32 C-layout regs (m=(r&3)+8*(r>>2)+4*hh, col=l) -> two bf16 B-fragments
// (k=hh*8+j): f0 = m 0..15, f1 = m 16..31. (Verified R3-R9.)
static __device__ __forceinline__ void regs_to_bfrags(const float16v c, int hh,
                                                      short8& f0, short8& f1) {
  unsigned int a0 = pk2f(c[0], c[1]),   a1 = pk2f(c[2], c[3]);
  unsigned int a2 = pk2f(c[4], c[5]),   a3 = pk2f(c[6], c[7]);
  unsigned int a4 = pk2f(c[8], c[9]),   a5 = pk2f(c[10], c[11]);
  unsigned int a6 = pk2f(c[12], c[13]), a7 = pk2f(c[14], c[15]);
  unsigned int x0 = __shfl_xor(hh ? a0 : a2, 32);
  unsigned int x1 = __shfl_xor(hh ? a1 : a3, 32);
  unsigned int x2 = __shfl_xor(hh ? a4 : a6, 32);
  unsigned int x3 = __shfl_xor(hh ? a5 : a7, 32);
  uint4 u0 = {hh ? x0 : a0, hh ? x1 : a1, hh ? a2 : x0, hh ? a3 : x1};
  uint4 u1 = {hh ? x2 : a4, hh ? x3 : a5, hh ? a6 : x2, hh ? a7 : x3};
  f0 = __builtin_bit_cast(short8, u0);
  f1 = __builtin_bit_cast(short8, u1);
}

// Same structure at BYTE granularity for fp8 e4m3 B-frags (Q scaled by 64).
static __device__ __forceinline__ void regs_to_f8frags(const float16v c, int hh,
                                                       long long& f0, long long& f1) {
  const float s = 64.0f;  // lift Q (rms ~0.011) out of e4m3 subnormal range
  int v0 = __builtin_amdgcn_cvt_pk_fp8_f32(c[0] * s, c[1] * s, 0, false);
  v0 = __builtin_amdgcn_cvt_pk_fp8_f32(c[2] * s, c[3] * s, v0, true);
  int v1 = __builtin_amdgcn_cvt_pk_fp8_f32(c[4] * s, c[5] * s, 0, false);
  v1 = __builtin_amdgcn_cvt_pk_fp8_f32(c[6] * s, c[7] * s, v1, true);
  int v2 = __builtin_amdgcn_cvt_pk_fp8_f32(c[8] * s, c[9] * s, 0, false);
  v2 = __builtin_amdgcn_cvt_pk_fp8_f32(c[10] * s, c[11] * s, v2, true);
  int v3 = __builtin_amdgcn_cvt_pk_fp8_f32(c[12] * s, c[13] * s, 0, false);
  v3 = __builtin_amdgcn_cvt_pk_fp8_f32(c[14] * s, c[15] * s, v3, true);
  int t0 = __shfl_xor(hh ? v0 : v1, 32);
  int t1 = __shfl_xor(hh ? v2 : v3, 32);
  f0 = hh ? mk64((unsigned)t0, (unsigned)v1) : mk64((unsigned)v0, (unsigned)t0);
  f1 = hh ? mk64((unsigned)t1, (unsigned)v3) : mk64((unsigned)v2, (unsigned)t1);
}

// exp2(s/64) (Q was scaled x64; W pre-scaled by log2e), row-sum, pack bf16.
static __device__ __forceinline__ void regs_to_pfrags(const float16v s, int hh,
                                                      float& lsum, short8& f0,
                                                      short8& f1) {
  float e[16];
  float acc = 0.0f;
#pragma unroll
  for (int i = 0; i < 16; i++) { e[i] = fast_exp2(s[i] * 0.015625f); acc += e[i]; }
  lsum += acc;
  unsigned int a0 = pk2f(e[0], e[1]),   a1 = pk2f(e[2], e[3]);
  unsigned int a2 = pk2f(e[4], e[5]),   a3 = pk2f(e[6], e[7]);
  unsigned int a4 = pk2f(e[8], e[9]),   a5 = pk2f(e[10], e[11]);
  unsigned int a6 = pk2f(e[12], e[13]), a7 = pk2f(e[14], e[15]);
  unsigned int x0 = __shfl_xor(hh ? a0 : a2, 32);
  unsigned int x1 = __shfl_xor(hh ? a1 : a3, 32);
  unsigned int x2 = __shfl_xor(hh ? a4 : a6, 32);
  unsigned int x3 = __shfl_xor(hh ? a5 : a7, 32);
  uint4 u0 = {hh ? x0 : a0, hh ? x1 : a1, hh ? a2 : x0, hh ? a3 : x1};
  uint4 u1 = {hh ? x2 : a4, hh ? x3 : a5, hh ? a6 : x2, hh ? a7 : x3};
  f0 = __builtin_bit_cast(short8, u0);
  f1 = __builtin_bit_cast(short8, u1);
}

// ---- staging helpers (verified R7-R9) ----
static __device__ __forceinline__ void stage_64x256(const char* gbase, size_t stride,
                                                    int colOff, char* lds, int wave,
                                                    int lane) {
#pragma unroll
  for (int i = 0; i < 4; i++) {
    int r = wave * 16 + i * 4 + (lane >> 4);
    int us = (lane & 15) ^ (r & 15);
    load_lds16(gbase + (size_t)r * stride + colOff + us * 16,
               lds + (wave * 16 + i * 4) * 256);
  }
}
static __device__ __forceinline__ void stage_128x256(const char* gbase, size_t stride,
                                                     char* lds, int wave, int lane) {
#pragma unroll
  for (int i = 0; i < 8; i++) {
    int r = wave * 32 + i * 4 + (lane >> 4);
    int us = (lane & 15) ^ (r & 15);
    load_lds16(gbase + (size_t)r * stride + us * 16, lds + (wave * 32 + i * 4) * 256);
  }
}
// 128 rows x 128 B (bf16) -> 64 macro-rows x 256 B, macro-swizzled.
static __device__ __forceinline__ void stage_128x128(const char* gbase, size_t stride,
                                                     int colOff, char* lds, int wave,
                                                     int lane) {
#pragma unroll
  for (int i = 0; i < 4; i++) {
    int m = wave * 16 + i * 4 + (lane >> 4);
    int u = (lane & 15) ^ (m & 15);
    int grow = 2 * m + (u >> 3);
    load_lds16(gbase + (size_t)grow * stride + colOff + (u & 7) * 16,
               lds + (wave * 16 + i * 4) * 256);
  }
}
// 64 fp8 key-rows x 128 B -> 32 macro-rows x 256 B, macro-swizzled (8 KB).
static __device__ __forceinline__ void stage_k8(const char* gbase, char* lds,
                                                int wave, int lane) {
#pragma unroll
  for (int i = 0; i < 2; i++) {
    int m = wave * 8 + i * 4 + (lane >> 4);
    int u = (lane & 15) ^ (m & 15);
    int grow = 2 * m + (u >> 3);
    load_lds16(gbase + (size_t)grow * 128 + (u & 7) * 16,
               lds + (wave * 8 + i * 4) * 256);
  }
}
static __device__ __forceinline__ short8 read_macro(const char* lds, int row, int kunit) {
  int m = row >> 1;
  int u = ((row & 1) << 3) | kunit;
  return *(const short8*)(lds + m * 256 + ((u ^ (m & 15)) * 16));
}

// ---- fused prep: blocks 0..15 convert X; blocks 16..95 convert W/V ----
__global__ __launch_bounds__(256)
void prep_kernel(const float* __restrict__ X, const float* __restrict__ W,
                 const float* __restrict__ V, unsigned short* __restrict__ Xb,
                 unsigned short* __restrict__ XbT, unsigned char* __restrict__ Xf8,
                 unsigned short* __restrict__ Wt, unsigned short* __restrict__ Vt) {
  const int tid = threadIdx.x;
  __shared__ __align__(16) unsigned short Lt[128 * 136];
  if (blockIdx.x < 16) {
    const int n0 = blockIdx.x * 128;
    for (int i = tid; i < 128 * 32; i += 256) {
      int row = i >> 5, c4 = (i & 31) * 4;
      float4v x = *(const float4v*)(X + (size_t)(n0 + row) * D + c4);
      unsigned long long p = pack4(x.x, x.y, x.z, x.w);
      *(unsigned long long*)(Lt + row * 136 + c4) = p;
      *(unsigned long long*)(Xb + (size_t)(n0 + row) * D + c4) = p;
    }
    __syncthreads();
    // XbT [d][n]
    for (int i = tid; i < 128 * 16; i += 256) {
      int d = i >> 4, g = i & 15;
      short8 v;
#pragma unroll
      for (int j = 0; j < 8; j++) v[j] = (short)Lt[(g * 8 + j) * 136 + d];
      *(short8*)(XbT + (size_t)d * N + n0 + g * 8) = v;
    }
    // Xf8 [n][d-permuted]: chunk c=2t+o holds d[32t+8o .. +8) ++ d[32t+16+8o .. +8)
    for (int i = tid; i < 128 * 8; i += 256) {
      int row = i >> 3, c = i & 7, t = c >> 1, o8 = (c & 1) * 8;
      const unsigned short* lp = Lt + row * 136;
      int d0 = t * 32 + o8, d1 = t * 32 + 16 + o8;
      short8 xa = *(const short8*)(lp + d0);
      short8 xb = *(const short8*)(lp + d1);
      int w0 = __builtin_amdgcn_cvt_pk_fp8_f32(bf2f(xa[0]), bf2f(xa[1]), 0, false);
      w0 = __builtin_amdgcn_cvt_pk_fp8_f32(bf2f(xa[2]), bf2f(xa[3]), w0, true);
      int w1 = __builtin_amdgcn_cvt_pk_fp8_f32(bf2f(xa[4]), bf2f(xa[5]), 0, false);
      w1 = __builtin_amdgcn_cvt_pk_fp8_f32(bf2f(xa[6]), bf2f(xa[7]), w1, true);
      int w2 = __builtin_amdgcn_cvt_pk_fp8_f32(bf2f(xb[0]), bf2f(xb[1]), 0, false);
      w2 = __builtin_amdgcn_cvt_pk_fp8_f32(bf2f(xb[2]), bf2f(xb[3]), w2, true);
      int w3 = __builtin_amdgcn_cvt_pk_fp8_f32(bf2f(xb[4]), bf2f(xb[5]), 0, false);
      w3 = __builtin_amdgcn_cvt_pk_fp8_f32(bf2f(xb[6]), bf2f(xb[7]), w3, true);
      uint4 st = {(unsigned)w0, (unsigned)w1, (unsigned)w2, (unsigned)w3};
      *(uint4*)(Xf8 + (size_t)(n0 + row) * 128 + c * 16) = st;
    }
  } else {
    const int b = blockIdx.x - 16;
    const int mat = (b >= H) ? 1 : 0;
    const int h = mat ? b - H : b;
    const float* src = (mat ? V : W) + (size_t)h * D * D;
    unsigned short* dst = (mat ? Vt : Wt) + (size_t)h * D * D;
    const float scale = mat ? 1.0f : 0.1275174313f;  // log2(e)/sqrt(128)
    for (int i = tid; i < 128 * 32; i += 256) {
      int d = i >> 5, e4 = (i & 31) * 4;
      float4v w = *(const float4v*)(src + d * D + e4);
      Lt[(e4 + 0) * 136 + d] = f32_to_bf16(w.x * scale);
      Lt[(e4 + 1) * 136 + d] = f32_to_bf16(w.y * scale);
      Lt[(e4 + 2) * 136 + d] = f32_to_bf16(w.z * scale);
      Lt[(e4 + 3) * 136 + d] = f32_to_bf16(w.w * scale);
    }
    __syncthreads();
    for (int i = tid; i < 128 * 16; i += 256) {
      int e = i >> 4, u = i & 15;
      *(uint4*)((char*)dst + (size_t)e * 256 + u * 16) =
          *(const uint4*)((const char*)Lt + (size_t)e * 272 + u * 16);
    }
  }
}

// ---- attention: split-k x2, fp8 S-phase, bf16 T-phase, 48 KB arena ----
__global__ __launch_bounds__(256)
void attn_kernel(const unsigned short* __restrict__ Xb,
                 const unsigned char* __restrict__ Xf8,
                 const unsigned short* __restrict__ XbT,
                 const unsigned short* __restrict__ Wt,
                 const unsigned short* __restrict__ Vt,
                 unsigned short* __restrict__ Opart, float* __restrict__ Lsum) {
  __shared__ __align__(16) char smem[49152];
  char* XA = smem;            // 16K: XbT dbuf A / Vt half0 / out staging
  char* XB = smem + 16384;    // 16K: XbT dbuf B / Vt half1 / out staging
  char* KA = smem + 32768;    // 8K: fp8 K dbuf A
  char* KB = smem + 40960;    // 8K: fp8 K dbuf B
  const int bx = blockIdx.x;
  const int kh = bx & 1;
  const int q0 = ((bx >> 1) & 15) << 7;
  const int h = bx >> 5;
  const int tid = threadIdx.x;
  const int wave = tid >> 6, lane = tid & 63;
  const int l = lane & 31, hh = lane >> 5;

  const char* XbB = (const char*)Xb;
  const char* Xf8B = (const char*)Xf8;
  const char* XbTB = (const char*)XbT;
  const char* WtB = (const char*)(Wt + (size_t)h * D * D);
  const char* VtB = (const char*)(Vt + (size_t)h * D * D);
  const int kbase = kh * (N / 2);

  // 1. Wt full-stage [0,32K), K-tile0 -> KA, Q-tile A-frags straight from L2
  stage_128x256(WtB, 256, smem, wave, lane);
  stage_k8(Xf8B + (size_t)kbase * 128, KA, wave, lane);
  short8 xfr[8];
#pragma unroll
  for (int dk = 0; dk < 8; dk++)
    xfr[dk] = *(const short8*)(XbB + (size_t)(q0 + wave * 32 + l) * 256 + dk * 32 + hh * 16);
  __syncthreads();

  // 2. Q = Wt-frags x X-frags (per wave: its 32 q)
  float16v qa[4];
#pragma unroll
  for (int et = 0; et < 4; et++) qa[et] = (float16v)0.0f;
#pragma unroll
  for (int et = 0; et < 4; et++) {
    const int r = et * 32 + l;
#pragma unroll
    for (int dk = 0; dk < 8; dk++) {
      short8 wa = *(const short8*)(smem + r * 256 + (((2 * dk + hh) ^ (r & 15)) * 16));
      qa[et] = MFMA32(wa, xfr[dk], qa[et]);
    }
  }
  long long qf8[8];
#pragma unroll
  for (int et = 0; et < 4; et++)
    regs_to_f8frags(qa[et], hh, qf8[2 * et], qf8[2 * et + 1]);

  float16v Tacc[4];
#pragma unroll
  for (int dt = 0; dt < 4; dt++) Tacc[dt] = (float16v)0.0f;
  float lsum = 0.0f;
  __syncthreads();  // Wt reads done; [0,32K) free

  // 3. XbT tile0 -> XA
  stage_128x128(XbTB, 4096, kbase * 2, XA, wave, lane);
  __syncthreads();

  // 4. main loop, double-buffered, 1 barrier/tile
  for (int kt = 0; kt < NT; kt++) {
    const char* curK = (kt & 1) ? KB : KA;
    const char* curX = (kt & 1) ? XB : XA;
    char* altK = (kt & 1) ? KA : KB;
    char* altX = (kt & 1) ? XA : XB;
    if (kt + 1 < NT) {
      const int k0n = kbase + (kt + 1) * 64;
      stage_k8(Xf8B + (size_t)k0n * 128, altK, wave, lane);
      stage_128x128(XbTB, 4096, k0n * 2, altX, wave, lane);
    } else {
      stage_64x256(VtB, 256, 0, altX, wave, lane);  // Vt rows 0..63 -> XA
    }
#pragma unroll
    for (int ksub = 0; ksub < 2; ksub++) {
      float16v s = (float16v)0.0f;
      const int krow = ksub * 32 + l;
      const int mb = (krow >> 1) * 256, m16 = (krow >> 1) & 15;
      const int rsel = (krow & 1) << 3;
#pragma unroll
      for (int t = 0; t < 4; t++) {
        int u = (rsel | (t * 2 + hh)) ^ m16;
        uint4 w = *(const uint4*)(curK + mb + u * 16);
        s = MFMA8(mk64(w.x, w.y), qf8[2 * t], s);
        s = MFMA8(mk64(w.z, w.w), qf8[2 * t + 1], s);
      }
      short8 pf0, pf1;
      regs_to_pfrags(s, hh, lsum, pf0, pf1);
#pragma unroll
      for (int kk = 0; kk < 2; kk++) {
        short8 pf = kk ? pf1 : pf0;
#pragma unroll
        for (int dt = 0; dt < 4; dt++) {
          short8 xt = read_macro(curX, dt * 32 + l, ksub * 4 + kk * 2 + hh);
          Tacc[dt] = MFMA32(xt, pf, Tacc[dt]);
        }
      }
    }
    __syncthreads();
  }

  float tot = lsum + __shfl_xor(lsum, 32);
  if (hh == 0) Lsum[(size_t)(h * 2 + kh) * N + q0 + wave * 32 + l] = tot;

  // 5. epilogue: O^T[e][q] = V^T[e][d] @ T^T[d][q]; Vt half1 prefetch
  stage_64x256(VtB + 64 * 256, 256, 0, XB, wave, lane);  // rows 64..127 -> XB
  short8 tb[8];
#pragma unroll
  for (int dt = 0; dt < 4; dt++)
    regs_to_bfrags(Tacc[dt], hh, tb[2 * dt], tb[2 * dt + 1]);

  float16v oacc[4];
#pragma unroll
  for (int et = 0; et < 4; et++) oacc[et] = (float16v)0.0f;
#pragma unroll
  for (int et = 0; et < 2; et++) {  // Vt half0 (XA, staged during kt=15)
    const int r = et * 32 + l;
#pragma unroll
    for (int dk = 0; dk < 8; dk++) {
      short8 va = *(const short8*)(XA + r * 256 + (((2 * dk + hh) ^ (r & 15)) * 16));
      oacc[et] = MFMA32(va, tb[dk], oacc[et]);
    }
  }
  __syncthreads();  // Vt half1 ready
#pragma unroll
  for (int et = 2; et < 4; et++) {
    const int r = (et - 2) * 32 + l;
#pragma unroll
    for (int dk = 0; dk < 8; dk++) {
      short8 va = *(const short8*)(XB + r * 256 + (((2 * dk + hh) ^ (r & 15)) * 16));
      oacc[et] = MFMA32(va, tb[dk], oacc[et]);
    }
  }

  // 6. transpose via [0,32K) + coalesced fp16 partial store
  unsigned short* Oph = Opart + (size_t)(h * 2 + kh) * N * D;
#pragma unroll
  for (int pass = 0; pass < 2; pass++) {
    __syncthreads();
    const int qrow = wave * 32 + l;
#pragma unroll
    for (int etL = 0; etL < 2; etL++) {
      int et = pass * 2 + etL;
#pragma unroll
      for (int g = 0; g < 4; g++) {
        int unit = etL * 8 + 2 * g + hh;
        float4v v;
        v.x = oacc[et][4 * g + 0];
        v.y = oacc[et][4 * g + 1];
        v.z = oacc[et][4 * g + 2];
        v.w = oacc[et][4 * g + 3];
        *(float4v*)(smem + qrow * 256 + ((unit ^ (qrow & 15)) * 16)) = v;
      }
    }
    __syncthreads();
#pragma unroll
    for (int i = 0; i < 8; i++) {
      int idx = i * 256 + tid;
      int qr = idx >> 4, up = idx & 15, u = up ^ (qr & 15);
      float4v v = *(const float4v*)(smem + qr * 256 + up * 16);
      auto h0 = __builtin_amdgcn_cvt_pkrtz(v.x, v.y);
      auto h1 = __builtin_amdgcn_cvt_pkrtz(v.z, v.w);
      uint2 st = {__builtin_bit_cast(unsigned int, h0),
                  __builtin_bit_cast(unsigned int, h1)};
      *(uint2*)(Oph + (size_t)(q0 + qr) * D + pass * 64 + u * 4) = st;
    }
  }
}

// ---- reduce: out[n][e] = sum_h (O[h,0]+O[h,1]) / (l[h,0]+l[h,1]) ----
__global__ __launch_bounds__(256)
void reduce_kernel(const unsigned short* __restrict__ Opart,
                   const float* __restrict__ Lsum, float* __restrict__ out) {
  int idx = blockIdx.x * 256 + threadIdx.x;  // float4 unit, 65536 total
  int n = idx >> 5;
  const uint2* base = (const uint2*)Opart;
  float4v acc = (float4v)0.0f;
#pragma unroll 8
  for (int h = 0; h < H; h++) {
    float lt = Lsum[(size_t)(2 * h) * N + n] + Lsum[(size_t)(2 * h + 1) * N + n];
    float il = __builtin_amdgcn_rcpf(lt);
    uint2 a = base[(size_t)(2 * h) * (N * D / 4) + idx];
    uint2 b = base[(size_t)(2 * h + 1) * (N * D / 4) + idx];
    float4v fa = __builtin_convertvector(__builtin_bit_cast(half4v, a), float4v);
    float4v fb = __builtin_convertvector(__builtin_bit_cast(half4v, b), float4v);
    acc += (fa + fb) * il;
  }
  *(float4v*)(out + (size_t)idx * 4) = acc;
}

extern "C" void kernel_launch(void* const* d_in, const int* in_sizes, int n_in,
                              void* d_out, int out_size, void* d_ws, size_t ws_size,
                              hipStream_t stream) {
  const float* X = (const float*)d_in[0];
  const float* W = (const float*)d_in[1];
  const float* V = (const float*)d_in[2];
  float* out = (float*)d_out;

  unsigned short* Xb = (unsigned short*)d_ws;        // N*D bf16
  unsigned short* XbT = Xb + (size_t)N * D;          // D*N bf16
  unsigned short* Wt = XbT + (size_t)N * D;          // H*D*D bf16 (log2e-scaled)
  unsigned short* Vt = Wt + (size_t)H * D * D;       // H*D*D bf16
  unsigned char* Xf8 = (unsigned char*)(Vt + (size_t)H * D * D);  // N*D fp8 (perm)
  unsigned short* Opart = (unsigned short*)(Xf8 + (size_t)N * D); // H*2*N*D fp16
  float* Lsum = (float*)(Opart + (size_t)H * 2 * N * D);          // H*2*N fp32

  prep_kernel<<<dim3(16 + 2 * H), 256, 0, stream>>>(X, W, V, Xb, XbT, Xf8, Wt, Vt);
  attn_kernel<<<dim3(NT * 2 * H), 256, 0, stream>>>(Xb, Xf8, XbT, Wt, Vt, Opart, Lsum);
  reduce_kernel<<<dim3(N * D / 4 / 256), 256, 0, stream>>>(Opart, Lsum, out);
}